// Round 1
// baseline (956.858 us; speedup 1.0000x reference)
//
#include <hip/hip_runtime.h>
#include <cstdint>
#include <cmath>
#include <cstddef>

typedef unsigned int u32;
typedef unsigned short u16;
typedef __bf16 bf16x8 __attribute__((ext_vector_type(8)));
typedef float f32x4 __attribute__((ext_vector_type(4)));
typedef u32 u32x4 __attribute__((ext_vector_type(4)));
typedef u32 u32x2 __attribute__((ext_vector_type(2)));

#define DEV static __device__ __forceinline__

// ---------- helpers ----------
DEV float bflo(u32 u) { return __uint_as_float(u << 16); }
DEV float bfhi(u32 u) { return __uint_as_float(u & 0xffff0000u); }
DEV u16 f2bf(float f) {               // RNE fp32 -> bf16
  u32 u = __float_as_uint(f);
  u += 0x7fffu + ((u >> 16) & 1u);
  return (u16)(u >> 16);
}
DEV float wredsum(float v) {
#pragma unroll
  for (int o = 32; o; o >>= 1) v += __shfl_xor(v, o, 64);
  return v;
}
DEV float wredmax(float v) {
#pragma unroll
  for (int o = 32; o; o >>= 1) v = fmaxf(v, __shfl_xor(v, o, 64));
  return v;
}

// ---------- generic fp32 -> bf16 cast (n multiple of 1024) ----------
__global__ __launch_bounds__(256) void cast_f32_bf16(const float* __restrict__ in,
                                                     u16* __restrict__ out) {
  const size_t idx = ((size_t)blockIdx.x * 256 + threadIdx.x) * 4;
  const f32x4 v = *(const f32x4*)&in[idx];
  u32x2 r;
  r[0] = (u32)f2bf(v[0]) | ((u32)f2bf(v[1]) << 16);
  r[1] = (u32)f2bf(v[2]) | ((u32)f2bf(v[3]) << 16);
  *(u32x2*)&out[idx] = r;
}

// conv_w [64][64][32] (o,i,kk) fp32 -> Wc [64][2048] bf16 with Wc[o][kk*64+i]
__global__ __launch_bounds__(256) void cast_convw(const float* __restrict__ cw,
                                                  u16* __restrict__ wc) {
  const int idx = blockIdx.x * 256 + threadIdx.x;  // 131072 total
  const int o = idx >> 11;
  const int rest = idx & 2047;
  const int i = rest >> 5;
  const int kk = rest & 31;
  wc[(o << 11) + (kk << 6) + i] = f2bf(cw[idx]);
}

// ---------- MFMA GEMM: out[M,N] = A[M,K](bf16) * B[N,K](bf16)^T ----------
// 128x128 tile, BK=32, 256 threads (4 waves, 2x2 wave grid of 64x64)
template <int OUT_BF16>
__global__ __launch_bounds__(256) void gemm_bt(const u16* __restrict__ A,
                                               const u16* __restrict__ Bm,
                                               void* __restrict__ out,
                                               int M, int N, int K) {
  __shared__ u16 As[128 * 32];
  __shared__ u16 Bs[128 * 32];
  const int tid = threadIdx.x;
  const int lane = tid & 63;
  const int w = tid >> 6;
  const int row0 = blockIdx.x * 128;
  const int col0 = blockIdx.y * 128;
  const int wm = (w >> 1) * 64, wn = (w & 1) * 64;
  const int lr = lane & 15, lq = lane >> 4;

  f32x4 acc[4][4] = {};

  for (int k0 = 0; k0 < K; k0 += 32) {
    __syncthreads();
#pragma unroll
    for (int p = 0; p < 2; ++p) {
      const int idx = p * 256 + tid;
      const int r = idx >> 2, c = (idx & 3) * 8;
      *(u32x4*)&As[r * 32 + c] = *(const u32x4*)&A[(size_t)(row0 + r) * K + k0 + c];
      *(u32x4*)&Bs[r * 32 + c] = *(const u32x4*)&Bm[(size_t)(col0 + r) * K + k0 + c];
    }
    __syncthreads();
    bf16x8 af[4], bfr[4];
#pragma unroll
    for (int i = 0; i < 4; ++i) {
      af[i] = *(const bf16x8*)&As[(wm + i * 16 + lr) * 32 + lq * 8];
      bfr[i] = *(const bf16x8*)&Bs[(wn + i * 16 + lr) * 32 + lq * 8];
    }
#pragma unroll
    for (int i = 0; i < 4; ++i)
#pragma unroll
      for (int j = 0; j < 4; ++j)
        acc[i][j] = __builtin_amdgcn_mfma_f32_16x16x32_bf16(af[i], bfr[j], acc[i][j], 0, 0, 0);
  }
  // D layout: col = lane&15, row = (lane>>4)*4 + rr  [m89-verified]
#pragma unroll
  for (int i = 0; i < 4; ++i)
#pragma unroll
    for (int j = 0; j < 4; ++j)
#pragma unroll
      for (int rr = 0; rr < 4; ++rr) {
        const int gr = row0 + wm + i * 16 + lq * 4 + rr;
        const int gc = col0 + wn + j * 16 + lr;
        const float v = acc[i][j][rr];
        if (OUT_BF16)
          ((u16*)out)[(size_t)gr * N + gc] = f2bf(v);
        else
          ((float*)out)[(size_t)gr * N + gc] = v;
      }
}

// ---------- compression: conv(K=32,stride16) as GEMM + LN(64) + exact GELU ----------
// M = (B*H)*63 = 8064 rows, N = 64, K = 2048.  grid (63, 2): y=0 -> k, y=1 -> v
__global__ __launch_bounds__(256) void compress_kernel(const u16* __restrict__ qkv,
                                                       const u16* __restrict__ Wc,
                                                       const float* __restrict__ ln_w,
                                                       float* __restrict__ out_k,
                                                       float* __restrict__ out_v) {
  __shared__ u16 As[128 * 32];
  __shared__ u16 Bs[64 * 32];
  __shared__ float Cs[128][65];
  const int srcoff = 1024 + (int)blockIdx.y * 1024;
  float* outp = blockIdx.y ? out_v : out_k;
  const int tid = threadIdx.x;
  const int lane = tid & 63;
  const int w = tid >> 6;
  const int r0 = blockIdx.x * 128;
  const int lr = lane & 15, lq = lane >> 4;

  // precompute per-pass row decomposition (fixed across K loop)
  size_t rowbase[2];
#pragma unroll
  for (int p = 0; p < 2; ++p) {
    const int idx = p * 256 + tid;
    const int r = idx >> 2, c = (idx & 3) * 8;
    const int gr = r0 + r;
    const int bh = gr / 63;
    const int nb = gr - bh * 63;
    const int b = bh >> 4, h = bh & 15;
    rowbase[p] = (size_t)(b * 1024 + nb * 16) * 3072 + srcoff + h * 64 + c;
  }
  const int brow = tid >> 2, bcol = (tid & 3) * 8;

  f32x4 acc[2][4] = {};
  for (int k0 = 0; k0 < 2048; k0 += 32) {
    const int kk = k0 >> 6;
    const int i0 = k0 & 63;  // 0 or 32
    __syncthreads();
#pragma unroll
    for (int p = 0; p < 2; ++p) {
      const int idx = p * 256 + tid;
      const int r = idx >> 2, c = (idx & 3) * 8;
      *(u32x4*)&As[r * 32 + c] = *(const u32x4*)&qkv[rowbase[p] + (size_t)kk * 3072 + i0];
    }
    *(u32x4*)&Bs[brow * 32 + bcol] = *(const u32x4*)&Wc[(size_t)brow * 2048 + k0 + bcol];
    __syncthreads();
    bf16x8 af[2], bfr[4];
#pragma unroll
    for (int i = 0; i < 2; ++i) af[i] = *(const bf16x8*)&As[(w * 32 + i * 16 + lr) * 32 + lq * 8];
#pragma unroll
    for (int j = 0; j < 4; ++j) bfr[j] = *(const bf16x8*)&Bs[(j * 16 + lr) * 32 + lq * 8];
#pragma unroll
    for (int i = 0; i < 2; ++i)
#pragma unroll
      for (int j = 0; j < 4; ++j)
        acc[i][j] = __builtin_amdgcn_mfma_f32_16x16x32_bf16(af[i], bfr[j], acc[i][j], 0, 0, 0);
  }
  __syncthreads();
#pragma unroll
  for (int i = 0; i < 2; ++i)
#pragma unroll
    for (int j = 0; j < 4; ++j)
#pragma unroll
      for (int rr = 0; rr < 4; ++rr)
        Cs[w * 32 + i * 16 + lq * 4 + rr][j * 16 + lr] = acc[i][j][rr];
  __syncthreads();
  if (tid < 128) {
    const int r = tid;
    float s = 0.f, s2 = 0.f;
#pragma unroll 8
    for (int d = 0; d < 64; ++d) {
      const float x = Cs[r][d];
      s += x;
      s2 += x * x;
    }
    const float m = s * (1.f / 64.f);
    const float inv = rsqrtf(s2 * (1.f / 64.f) - m * m + 1e-5f);
    const size_t gr = (size_t)(r0 + r) * 64;
#pragma unroll 8
    for (int d = 0; d < 64; ++d) {
      const float z = (Cs[r][d] - m) * inv * ln_w[d];
      outp[gr + d] = 0.5f * z * (1.f + erff(z * 0.70710678118f));
    }
  }
}

// ---------- local banded attention (window 129) ----------
// grid (B*H, T/64); block 256. Writes pre-LN local_out.
__global__ __launch_bounds__(256) void local_attn(const u16* __restrict__ qkv,
                                                  float* __restrict__ loc) {
  __shared__ u16 Ks[192 * 66];   // [slot][d] bf16, pad 66
  __shared__ u16 Vt[64 * 194];   // [d][slot] bf16, pad 194
  __shared__ u16 Qs[64 * 64];    // [qi][d] bf16 (broadcast reads)
  const int bh = blockIdx.x;
  const int b = bh >> 4, h = bh & 15;
  const int i0 = blockIdx.y * 64;
  const int jbase = i0 - 128;
  const int tid = threadIdx.x;

  for (int idx = tid; idx < 192 * 32; idx += 256) {
    const int s = idx >> 5, c = idx & 31;
    const int j = jbase + s;
    u32 kv = 0, vv = 0;
    if (j >= 0) {
      const size_t rowoff = (size_t)(b * 1024 + j) * 3072 + h * 64 + c * 2;
      kv = *(const u32*)&qkv[rowoff + 1024];
      vv = *(const u32*)&qkv[rowoff + 2048];
    }
    *(u32*)&Ks[s * 66 + c * 2] = kv;
    Vt[(c * 2) * 194 + s] = (u16)(vv & 0xffffu);
    Vt[(c * 2 + 1) * 194 + s] = (u16)(vv >> 16);
  }
  for (int idx = tid; idx < 64 * 32; idx += 256) {
    const int qi = idx >> 5, c = idx & 31;
    *(u32*)&Qs[qi * 64 + c * 2] =
        *(const u32*)&qkv[(size_t)(b * 1024 + i0 + qi) * 3072 + h * 64 + c * 2];
  }
  __syncthreads();

  const int lane = tid & 63, w = tid >> 6;
  const u16* vtrow = &Vt[lane * 194];
  for (int sub = 0; sub < 16; ++sub) {
    const int qi = w * 16 + sub;
    const int i = i0 + qi;
    float sc[3] = {0.f, 0.f, 0.f};
#pragma unroll 8
    for (int d2 = 0; d2 < 32; ++d2) {
      const u32 qp = *(const u32*)&Qs[qi * 64 + d2 * 2];
      const float q0 = bflo(qp), q1 = bfhi(qp);
      const u32 k0p = *(const u32*)&Ks[lane * 66 + d2 * 2];
      const u32 k1p = *(const u32*)&Ks[(64 + lane) * 66 + d2 * 2];
      const u32 k2p = *(const u32*)&Ks[(128 + lane) * 66 + d2 * 2];
      sc[0] += q0 * bflo(k0p) + q1 * bfhi(k0p);
      sc[1] += q0 * bflo(k1p) + q1 * bfhi(k1p);
      sc[2] += q0 * bflo(k2p) + q1 * bfhi(k2p);
    }
    float m = -INFINITY;
#pragma unroll
    for (int c = 0; c < 3; ++c) {
      const int s = c * 64 + lane;
      const int j = jbase + s;
      const bool valid = (j >= 0) && (s >= qi) && (s <= qi + 128);
      sc[c] = valid ? sc[c] * 0.125f : -INFINITY;
      m = fmaxf(m, sc[c]);
    }
    m = wredmax(m);
    float p[3];
    p[0] = __expf(sc[0] - m);
    p[1] = __expf(sc[1] - m);
    p[2] = __expf(sc[2] - m);
    const float inv = 1.0f / wredsum(p[0] + p[1] + p[2]);
    float o = 0.f;
#pragma unroll
    for (int c = 0; c < 3; ++c) {
      const float pcv = p[c] * inv;
#pragma unroll 8
      for (int l = 0; l < 64; l += 2) {
        const u32 vp = *(const u32*)&vtrow[c * 64 + l];
        o += __shfl(pcv, l, 64) * bflo(vp) + __shfl(pcv, l + 1, 64) * bfhi(vp);
      }
    }
    loc[(size_t)(b * 1024 + i) * 1024 + h * 64 + lane] = o;
  }
}

// ---------- compressed-KV attention (63 blocks, block-causal) ----------
// grid (B*H, T/64); block 256.
__global__ __launch_bounds__(256) void comp_attn(const u16* __restrict__ qkv,
                                                 const float* __restrict__ kc,
                                                 const float* __restrict__ vc,
                                                 float* __restrict__ outc) {
  __shared__ u16 Kc[64 * 66];    // [j][d] bf16 (row 63 unused)
  __shared__ float Vct[64 * 65]; // [d][j] fp32
  __shared__ u16 Qs[64 * 64];
  const int bh = blockIdx.x;
  const int b = bh >> 4, h = bh & 15;
  const int i0 = blockIdx.y * 64;
  const int tid = threadIdx.x;
  const size_t kbase = (size_t)bh * 63 * 64;

  for (int idx = tid; idx < 63 * 64; idx += 256) {
    const int j = idx >> 6, d = idx & 63;
    Kc[j * 66 + d] = f2bf(kc[kbase + idx]);
    Vct[d * 65 + j] = vc[kbase + idx];
  }
  for (int idx = tid; idx < 64 * 32; idx += 256) {
    const int qi = idx >> 5, c = idx & 31;
    *(u32*)&Qs[qi * 64 + c * 2] =
        *(const u32*)&qkv[(size_t)(b * 1024 + i0 + qi) * 3072 + h * 64 + c * 2];
  }
  __syncthreads();

  const int lane = tid & 63, w = tid >> 6;
  const u16* krow = &Kc[lane * 66];
  const float* vrow = &Vct[lane * 65];
  for (int sub = 0; sub < 16; ++sub) {
    const int qi = w * 16 + sub;
    const int i = i0 + qi;
    float sc = 0.f;
#pragma unroll 8
    for (int d2 = 0; d2 < 32; ++d2) {
      const u32 qp = *(const u32*)&Qs[qi * 64 + d2 * 2];
      const u32 kp = *(const u32*)&krow[d2 * 2];
      sc += bflo(qp) * bflo(kp) + bfhi(qp) * bfhi(kp);
    }
    const bool valid = (lane <= i) && (lane < 63);
    sc = valid ? sc * 0.125f : -INFINITY;
    const float m = wredmax(sc);
    float p = __expf(sc - m);
    const float inv = 1.0f / wredsum(p);
    p *= inv;
    float o = 0.f;
#pragma unroll 7
    for (int l = 0; l < 63; ++l) {
      o += __shfl(p, l, 64) * vrow[l];
    }
    outc[(size_t)(b * 1024 + i) * 1024 + h * 64 + lane] = o;
  }
}

// ---------- row LayerNorm over C=1024, in-place ----------
__global__ __launch_bounds__(256) void row_ln(float* __restrict__ x,
                                              const float* __restrict__ wt) {
  const int row = blockIdx.x, tid = threadIdx.x;
  const size_t base = (size_t)row * 1024 + tid * 4;
  const f32x4 v = *(const f32x4*)&x[base];
  float s = v[0] + v[1] + v[2] + v[3];
  float s2 = v[0] * v[0] + v[1] * v[1] + v[2] * v[2] + v[3] * v[3];
  s = wredsum(s);
  s2 = wredsum(s2);
  __shared__ float rs[4], rs2[4];
  const int w = tid >> 6, lane = tid & 63;
  if (!lane) {
    rs[w] = s;
    rs2[w] = s2;
  }
  __syncthreads();
  s = rs[0] + rs[1] + rs[2] + rs[3];
  s2 = rs2[0] + rs2[1] + rs2[2] + rs2[3];
  const float m = s * (1.f / 1024.f);
  const float inv = rsqrtf(s2 * (1.f / 1024.f) - m * m + 1e-5f);
  const f32x4 wv = *(const f32x4*)&wt[tid * 4];
  f32x4 o;
#pragma unroll
  for (int k = 0; k < 4; ++k) o[k] = (v[k] - m) * inv * wv[k];
  *(f32x4*)&x[base] = o;
}

// ---------- gating GEMV: hraw[b,o] = feats[b,:] . gate_w1[o,:] ----------
// grid (B, 4); block 256; o = chunk*256 + tid
__global__ __launch_bounds__(256) void gate_gemv(const float* __restrict__ locn,
                                                 const float* __restrict__ comp,
                                                 const float* __restrict__ w1,
                                                 float* __restrict__ hraw) {
  __shared__ float fs[2048];
  const int b = blockIdx.x, chunk = blockIdx.y, tid = threadIdx.x;
  const size_t rb = ((size_t)b * 1024 + 1023) * 1024;
  for (int idx = tid; idx < 1024; idx += 256) {
    fs[idx] = locn[rb + idx];
    fs[1024 + idx] = comp[rb + idx];
  }
  __syncthreads();
  const int o = chunk * 256 + tid;
  const float* wr = &w1[(size_t)o * 2048];
  float acc = 0.f;
#pragma unroll 4
  for (int c = 0; c < 2048; c += 4) {
    const f32x4 wv = *(const f32x4*)&wr[c];
    const f32x4 fv = *(const f32x4*)&fs[c];
    acc += fv[0] * wv[0] + fv[1] * wv[1] + fv[2] * wv[2] + fv[3] * wv[3];
  }
  hraw[b * 1024 + o] = acc;
}

// ---------- gating finalize: LN + ReLU + 2-way GEMV + softmax ----------
__global__ __launch_bounds__(256) void gate_fin(const float* __restrict__ hraw,
                                                const float* __restrict__ lnw,
                                                const float* __restrict__ w2,
                                                float* __restrict__ gates) {
  const int b = blockIdx.x, tid = threadIdx.x;
  const f32x4 v = *(const f32x4*)&hraw[(size_t)b * 1024 + tid * 4];
  float s = v[0] + v[1] + v[2] + v[3];
  float s2 = v[0] * v[0] + v[1] * v[1] + v[2] * v[2] + v[3] * v[3];
  s = wredsum(s);
  s2 = wredsum(s2);
  __shared__ float rs[4], rs2[4];
  const int w = tid >> 6, lane = tid & 63;
  if (!lane) {
    rs[w] = s;
    rs2[w] = s2;
  }
  __syncthreads();
  s = rs[0] + rs[1] + rs[2] + rs[3];
  s2 = rs2[0] + rs2[1] + rs2[2] + rs2[3];
  const float m = s * (1.f / 1024.f);
  const float inv = rsqrtf(s2 * (1.f / 1024.f) - m * m + 1e-5f);
  float p0 = 0.f, p1 = 0.f;
#pragma unroll
  for (int k = 0; k < 4; ++k) {
    float hh = (v[k] - m) * inv * lnw[tid * 4 + k];
    hh = fmaxf(hh, 0.f);
    p0 += hh * w2[tid * 4 + k];
    p1 += hh * w2[1024 + tid * 4 + k];
  }
  p0 = wredsum(p0);
  p1 = wredsum(p1);
  __syncthreads();
  if (!lane) {
    rs[w] = p0;
    rs2[w] = p1;
  }
  __syncthreads();
  if (tid == 0) {
    const float l0 = rs[0] + rs[1] + rs[2] + rs[3];
    const float l1 = rs2[0] + rs2[1] + rs2[2] + rs2[3];
    const float mm = fmaxf(l0, l1);
    const float e0 = __expf(l0 - mm), e1 = __expf(l1 - mm);
    const float iv = 1.f / (e0 + e1);
    gates[b * 2] = e0 * iv;
    gates[b * 2 + 1] = e1 * iv;
  }
}

// ---------- combine + cast to bf16 ----------
__global__ __launch_bounds__(256) void combine_cast(const float* __restrict__ locn,
                                                    const float* __restrict__ comp,
                                                    const float* __restrict__ gates,
                                                    u16* __restrict__ outb) {
  const size_t idx = ((size_t)blockIdx.x * 256 + threadIdx.x) * 4;
  const int b = (int)(idx >> 20);
  const float g0 = gates[2 * b], g1 = gates[2 * b + 1];
  const f32x4 a = *(const f32x4*)&locn[idx];
  const f32x4 c = *(const f32x4*)&comp[idx];
  u32x2 r;
  r[0] = (u32)f2bf(g0 * a[0] + g1 * c[0]) | ((u32)f2bf(g0 * a[1] + g1 * c[1]) << 16);
  r[1] = (u32)f2bf(g0 * a[2] + g1 * c[2]) | ((u32)f2bf(g0 * a[3] + g1 * c[3]) << 16);
  *(u32x2*)&outb[idx] = r;
}

// ---------- launcher ----------
extern "C" void kernel_launch(void* const* d_in, const int* in_sizes, int n_in,
                              void* d_out, int out_size, void* d_ws, size_t ws_size,
                              hipStream_t stream) {
  const float* x = (const float*)d_in[0];        // [8,1024,1024]
  const float* c_attn_w = (const float*)d_in[1]; // [3072,1024]
  const float* conv_w = (const float*)d_in[2];   // [64,64,32]
  const float* ln_comp_w = (const float*)d_in[3];// [64]
  const float* ln_local_w = (const float*)d_in[4];// [1024]
  const float* gate_w1 = (const float*)d_in[5];  // [1024,2048]
  const float* gate_ln_w = (const float*)d_in[6];// [1024]
  const float* gate_w2 = (const float*)d_in[7];  // [2,1024]
  const float* c_proj_w = (const float*)d_in[8]; // [1024,1024]
  float* y = (float*)d_out;

  char* ws = (char*)d_ws;
  size_t off = 0;
  auto alloc = [&](size_t bytes) -> void* {
    void* p = ws + off;
    off += (bytes + 255) & ~(size_t)255;
    return p;
  };
  u16* qkvb = (u16*)alloc((size_t)8192 * 3072 * 2);   // bf16 qkv
  u16* xb = (u16*)alloc((size_t)8192 * 1024 * 2);
  u16* wab = (u16*)alloc((size_t)3072 * 1024 * 2);
  u16* wpb = (u16*)alloc((size_t)1024 * 1024 * 2);
  u16* wcb = (u16*)alloc((size_t)64 * 2048 * 2);
  float* kc = (float*)alloc((size_t)8064 * 64 * 4);
  float* vc = (float*)alloc((size_t)8064 * 64 * 4);
  float* locn = (float*)alloc((size_t)8192 * 1024 * 4); // local_out -> LN in place
  float* comp = (float*)alloc((size_t)8192 * 1024 * 4);
  float* hraw = (float*)alloc((size_t)8192 * 4);
  float* gates = (float*)alloc(64);
  u16* combb = (u16*)alloc((size_t)8192 * 1024 * 2);

  // casts
  cast_f32_bf16<<<8192, 256, 0, stream>>>(x, xb);
  cast_f32_bf16<<<3072, 256, 0, stream>>>(c_attn_w, wab);
  cast_f32_bf16<<<1024, 256, 0, stream>>>(c_proj_w, wpb);
  cast_convw<<<512, 256, 0, stream>>>(conv_w, wcb);

  // qkv = x @ c_attn_w^T  (bf16 out)
  gemm_bt<1><<<dim3(64, 24), 256, 0, stream>>>(xb, wab, qkvb, 8192, 3072, 1024);

  // compression (k and v)
  compress_kernel<<<dim3(63, 2), 256, 0, stream>>>(qkvb, wcb, ln_comp_w, kc, vc);

  // attentions
  local_attn<<<dim3(128, 16), 256, 0, stream>>>(qkvb, locn);
  comp_attn<<<dim3(128, 16), 256, 0, stream>>>(qkvb, kc, vc, comp);

  // LN of local_out (in place)
  row_ln<<<8192, 256, 0, stream>>>(locn, ln_local_w);

  // gating
  gate_gemv<<<dim3(8, 4), 256, 0, stream>>>(locn, comp, gate_w1, hraw);
  gate_fin<<<8, 256, 0, stream>>>(hraw, gate_ln_w, gate_w2, gates);

  // combine + cast
  combine_cast<<<8192, 256, 0, stream>>>(locn, comp, gates, combb);

  // y = combined @ c_proj_w^T (fp32 out)
  gemm_bt<0><<<dim3(64, 8), 256, 0, stream>>>(combb, wpb, y, 8192, 1024, 1024);
}

// Round 2
// 408.160 us; speedup vs baseline: 2.3443x; 2.3443x over previous
//
#include <hip/hip_runtime.h>
#include <cstdint>
#include <cmath>
#include <cstddef>

typedef unsigned int u32;
typedef unsigned short u16;
typedef __bf16 bf16x8 __attribute__((ext_vector_type(8)));
typedef float f32x4 __attribute__((ext_vector_type(4)));
typedef u32 u32x4 __attribute__((ext_vector_type(4)));
typedef u32 u32x2 __attribute__((ext_vector_type(2)));

#define DEV static __device__ __forceinline__

// ---------- helpers ----------
DEV float bflo(u32 u) { return __uint_as_float(u << 16); }
DEV float bfhi(u32 u) { return __uint_as_float(u & 0xffff0000u); }
DEV u16 f2bf(float f) {               // RNE fp32 -> bf16
  u32 u = __float_as_uint(f);
  u += 0x7fffu + ((u >> 16) & 1u);
  return (u16)(u >> 16);
}
DEV float wredsum(float v) {
#pragma unroll
  for (int o = 32; o; o >>= 1) v += __shfl_xor(v, o, 64);
  return v;
}

// async global->LDS, 16B per lane. LDS dest is wave-uniform base + lane*16.
DEV void gload_lds16(const u16* g, u16* lds_base) {
  __builtin_amdgcn_global_load_lds((const __attribute__((address_space(1))) void*)g,
                                   (__attribute__((address_space(3))) void*)lds_base,
                                   16, 0, 0);
}

// ---------- generic fp32 -> bf16 cast (n multiple of 1024) ----------
__global__ __launch_bounds__(256) void cast_f32_bf16(const float* __restrict__ in,
                                                     u16* __restrict__ out) {
  const size_t idx = ((size_t)blockIdx.x * 256 + threadIdx.x) * 4;
  const f32x4 v = *(const f32x4*)&in[idx];
  u32x2 r;
  r[0] = (u32)f2bf(v[0]) | ((u32)f2bf(v[1]) << 16);
  r[1] = (u32)f2bf(v[2]) | ((u32)f2bf(v[3]) << 16);
  *(u32x2*)&out[idx] = r;
}

// conv_w [64][64][32] (o,i,kk) fp32 -> Wc [64][2048] bf16 with Wc[o][kk*64+i]
__global__ __launch_bounds__(256) void cast_convw(const float* __restrict__ cw,
                                                  u16* __restrict__ wc) {
  const int idx = blockIdx.x * 256 + threadIdx.x;  // 131072 total
  const int o = idx >> 11;
  const int rest = idx & 2047;
  const int i = rest >> 5;
  const int kk = rest & 31;
  wc[(o << 11) + (kk << 6) + i] = f2bf(cw[idx]);
}

// ---------- MFMA GEMM: out[M,N] = A[M,K](bf16) * B[N,K](bf16)^T ----------
// 128x128 tile, BK=32, 256 threads (4 waves, 2x2 wave grid of 64x64)
// Staging via global_load_lds width=16 (m97 pattern).
template <int OUT_BF16>
__global__ __launch_bounds__(256) void gemm_bt(const u16* __restrict__ A,
                                               const u16* __restrict__ Bm,
                                               void* __restrict__ out,
                                               int M, int N, int K) {
  __shared__ u16 As[128 * 32];
  __shared__ u16 Bs[128 * 32];
  const int tid = threadIdx.x;
  const int lane = tid & 63;
  const int w = tid >> 6;
  const int row0 = blockIdx.x * 128;
  const int col0 = blockIdx.y * 128;
  const int wm = (w >> 1) * 64, wn = (w & 1) * 64;
  const int lr = lane & 15, lq = lane >> 4;
  const int srow = lane >> 2;          // 0..15 row within 16-row chunk
  const int scol = (lane & 3) * 8;     // 0,8,16,24

  f32x4 acc[4][4] = {};

  for (int k0 = 0; k0 < K; k0 += 32) {
    __syncthreads();
#pragma unroll
    for (int p = 0; p < 2; ++p) {
      const int base_r = p * 64 + w * 16;   // wave-uniform
      gload_lds16(&A[(size_t)(row0 + base_r + srow) * K + k0 + scol], &As[base_r * 32]);
      gload_lds16(&Bm[(size_t)(col0 + base_r + srow) * K + k0 + scol], &Bs[base_r * 32]);
    }
    __syncthreads();
    bf16x8 af[4], bfr[4];
#pragma unroll
    for (int i = 0; i < 4; ++i) {
      af[i] = *(const bf16x8*)&As[(wm + i * 16 + lr) * 32 + lq * 8];
      bfr[i] = *(const bf16x8*)&Bs[(wn + i * 16 + lr) * 32 + lq * 8];
    }
#pragma unroll
    for (int i = 0; i < 4; ++i)
#pragma unroll
      for (int j = 0; j < 4; ++j)
        acc[i][j] = __builtin_amdgcn_mfma_f32_16x16x32_bf16(af[i], bfr[j], acc[i][j], 0, 0, 0);
  }
  // D layout: col = lane&15, row = (lane>>4)*4 + rr  [m89-verified]
#pragma unroll
  for (int i = 0; i < 4; ++i)
#pragma unroll
    for (int j = 0; j < 4; ++j)
#pragma unroll
      for (int rr = 0; rr < 4; ++rr) {
        const int gr = row0 + wm + i * 16 + lq * 4 + rr;
        const int gc = col0 + wn + j * 16 + lr;
        const float v = acc[i][j][rr];
        if (OUT_BF16)
          ((u16*)out)[(size_t)gr * N + gc] = f2bf(v);
        else
          ((float*)out)[(size_t)gr * N + gc] = v;
      }
}

// ---------- compression: conv(K=32,stride16) as GEMM + LN(64) + exact GELU ----------
// M = (B*H)*63 = 8064 rows, N = 64, K = 2048.  grid (63, 2): y=0 -> k, y=1 -> v
__global__ __launch_bounds__(256) void compress_kernel(const u16* __restrict__ qkv,
                                                       const u16* __restrict__ Wc,
                                                       const float* __restrict__ ln_w,
                                                       float* __restrict__ out_k,
                                                       float* __restrict__ out_v) {
  __shared__ u16 As[128 * 32];
  __shared__ u16 Bs[64 * 32];
  __shared__ float Cs[128][65];
  const int srcoff = 1024 + (int)blockIdx.y * 1024;
  float* outp = blockIdx.y ? out_v : out_k;
  const int tid = threadIdx.x;
  const int lane = tid & 63;
  const int w = tid >> 6;
  const int r0 = blockIdx.x * 128;
  const int lr = lane & 15, lq = lane >> 4;

  // precompute per-pass row decomposition (fixed across K loop)
  size_t rowbase[2];
#pragma unroll
  for (int p = 0; p < 2; ++p) {
    const int idx = p * 256 + tid;
    const int r = idx >> 2, c = (idx & 3) * 8;
    const int gr = r0 + r;
    const int bh = gr / 63;
    const int nb = gr - bh * 63;
    const int b = bh >> 4, h = bh & 15;
    rowbase[p] = (size_t)(b * 1024 + nb * 16) * 3072 + srcoff + h * 64 + c;
  }
  const int brow = tid >> 2, bcol = (tid & 3) * 8;

  f32x4 acc[2][4] = {};
  for (int k0 = 0; k0 < 2048; k0 += 32) {
    const int kk = k0 >> 6;
    const int i0 = k0 & 63;  // 0 or 32
    __syncthreads();
#pragma unroll
    for (int p = 0; p < 2; ++p) {
      const int idx = p * 256 + tid;
      const int r = idx >> 2, c = (idx & 3) * 8;
      *(u32x4*)&As[r * 32 + c] = *(const u32x4*)&qkv[rowbase[p] + (size_t)kk * 3072 + i0];
    }
    *(u32x4*)&Bs[brow * 32 + bcol] = *(const u32x4*)&Wc[(size_t)brow * 2048 + k0 + bcol];
    __syncthreads();
    bf16x8 af[2], bfr[4];
#pragma unroll
    for (int i = 0; i < 2; ++i) af[i] = *(const bf16x8*)&As[(w * 32 + i * 16 + lr) * 32 + lq * 8];
#pragma unroll
    for (int j = 0; j < 4; ++j) bfr[j] = *(const bf16x8*)&Bs[(j * 16 + lr) * 32 + lq * 8];
#pragma unroll
    for (int i = 0; i < 2; ++i)
#pragma unroll
      for (int j = 0; j < 4; ++j)
        acc[i][j] = __builtin_amdgcn_mfma_f32_16x16x32_bf16(af[i], bfr[j], acc[i][j], 0, 0, 0);
  }
  __syncthreads();
#pragma unroll
  for (int i = 0; i < 2; ++i)
#pragma unroll
    for (int j = 0; j < 4; ++j)
#pragma unroll
      for (int rr = 0; rr < 4; ++rr)
        Cs[w * 32 + i * 16 + lq * 4 + rr][j * 16 + lr] = acc[i][j][rr];
  __syncthreads();
  if (tid < 128) {
    const int r = tid;
    float s = 0.f, s2 = 0.f;
#pragma unroll 8
    for (int d = 0; d < 64; ++d) {
      const float x = Cs[r][d];
      s += x;
      s2 += x * x;
    }
    const float m = s * (1.f / 64.f);
    const float inv = rsqrtf(s2 * (1.f / 64.f) - m * m + 1e-5f);
    const size_t gr = (size_t)(r0 + r) * 64;
#pragma unroll 8
    for (int d = 0; d < 64; ++d) {
      const float z = (Cs[r][d] - m) * inv * ln_w[d];
      outp[gr + d] = 0.5f * z * (1.f + erff(z * 0.70710678118f));
    }
  }
}

// ---------- local banded attention (window 129), MFMA flash-style ----------
// grid (B*H, T/64); block 256 = 4 waves; wave w owns query rows w*16..w*16+15.
// Phase 1: S = Q*K^T (Ks in LDS region A). Phase 2: O = P*V (Vt overlays region A).
__global__ __launch_bounds__(256) void local_attn(const u16* __restrict__ qkv,
                                                  float* __restrict__ loc) {
  __shared__ __align__(16) char smem[53248];
  u16* Ks = (u16*)smem;            // [192][72] bf16, phase 1
  u16* Vt = (u16*)smem;            // [64][200] bf16, phase 2 (overlaps Ks)
  u16* Ps = (u16*)(smem + 27648);  // [64][200] bf16, phase 2
  const int bh = blockIdx.x;
  const int b = bh >> 4, h = bh & 15;
  const int i0 = blockIdx.y * 64;
  const int jbase = i0 - 128;
  const int tid = threadIdx.x;
  const int lane = tid & 63, w = tid >> 6;
  const int lr = lane & 15, lq = lane >> 4;

  // V into regs (held across phase 1), K into LDS. 192 rows x 8 chunks of 16B.
  u32x4 vreg[6];
#pragma unroll
  for (int c = 0; c < 6; ++c) {
    const int lin = c * 256 + tid;
    const int s = lin >> 3, d0 = (lin & 7) * 8;
    const int j = jbase + s;
    u32x4 kval = {0, 0, 0, 0}, vval = {0, 0, 0, 0};
    if (j >= 0) {
      const size_t ro = (size_t)(b * 1024 + j) * 3072 + h * 64 + d0;
      kval = *(const u32x4*)&qkv[ro + 1024];
      vval = *(const u32x4*)&qkv[ro + 2048];
    }
    vreg[c] = vval;
    *(u32x4*)&Ks[s * 72 + d0] = kval;
  }
  // Q fragments straight from global (A layout: m=lr, k=ks*32+lq*8)
  bf16x8 qf[2];
  {
    const size_t qrow = (size_t)(b * 1024 + i0 + w * 16 + lr) * 3072 + h * 64;
#pragma unroll
    for (int ks = 0; ks < 2; ++ks) qf[ks] = *(const bf16x8*)&qkv[qrow + ks * 32 + lq * 8];
  }
  __syncthreads();

  // S = Q*K^T : 12 col-tiles of 16, K-dim 64 (2 steps)
  f32x4 sa[12];
#pragma unroll
  for (int j = 0; j < 12; ++j) sa[j] = (f32x4){0.f, 0.f, 0.f, 0.f};
#pragma unroll
  for (int ks = 0; ks < 2; ++ks)
#pragma unroll
    for (int j = 0; j < 12; ++j) {
      const bf16x8 kf = *(const bf16x8*)&Ks[(j * 16 + lr) * 72 + ks * 32 + lq * 8];
      sa[j] = __builtin_amdgcn_mfma_f32_16x16x32_bf16(qf[ks], kf, sa[j], 0, 0, 0);
    }

  // mask + softmax (C layout: row = lq*4+rr, col = j*16+lr)
  const float NINF = -__builtin_inff();
  float mx[4] = {NINF, NINF, NINF, NINF};
#pragma unroll
  for (int j = 0; j < 12; ++j) {
    const int s = j * 16 + lr;
#pragma unroll
    for (int rr = 0; rr < 4; ++rr) {
      const int qi = w * 16 + lq * 4 + rr;
      const bool valid = (jbase + s >= 0) && (s >= qi) && (s <= qi + 128);
      const float v = valid ? sa[j][rr] * 0.125f : NINF;
      sa[j][rr] = v;
      mx[rr] = fmaxf(mx[rr], v);
    }
  }
#pragma unroll
  for (int rr = 0; rr < 4; ++rr)
#pragma unroll
    for (int o = 1; o < 16; o <<= 1) mx[rr] = fmaxf(mx[rr], __shfl_xor(mx[rr], o, 64));
  float sum[4] = {0.f, 0.f, 0.f, 0.f};
#pragma unroll
  for (int j = 0; j < 12; ++j)
#pragma unroll
    for (int rr = 0; rr < 4; ++rr) {
      const float p = __expf(sa[j][rr] - mx[rr]);
      sa[j][rr] = p;
      sum[rr] += p;
    }
#pragma unroll
  for (int rr = 0; rr < 4; ++rr) {
#pragma unroll
    for (int o = 1; o < 16; o <<= 1) sum[rr] += __shfl_xor(sum[rr], o, 64);
    sum[rr] = 1.0f / sum[rr];
  }
  __syncthreads();  // all waves done reading Ks before Vt overlays it

  // write normalized P (bf16) and Vt (transpose V regs into [d][s])
#pragma unroll
  for (int j = 0; j < 12; ++j)
#pragma unroll
    for (int rr = 0; rr < 4; ++rr)
      Ps[(w * 16 + lq * 4 + rr) * 200 + j * 16 + lr] = f2bf(sa[j][rr] * sum[rr]);
#pragma unroll
  for (int c = 0; c < 6; ++c) {
    const int lin = c * 256 + tid;
    const int s = lin >> 3, d0 = (lin & 7) * 8;
    const u32x4 val = vreg[c];
#pragma unroll
    for (int q = 0; q < 4; ++q) {
      Vt[(d0 + 2 * q) * 200 + s] = (u16)(val[q] & 0xffffu);
      Vt[(d0 + 2 * q + 1) * 200 + s] = (u16)(val[q] >> 16);
    }
  }
  __syncthreads();

  // O = P*V : 4 out-tiles of 16 dims, K-dim 192 (6 steps)
  f32x4 oa[4];
#pragma unroll
  for (int jt = 0; jt < 4; ++jt) oa[jt] = (f32x4){0.f, 0.f, 0.f, 0.f};
#pragma unroll
  for (int ks = 0; ks < 6; ++ks) {
    const bf16x8 pf = *(const bf16x8*)&Ps[(w * 16 + lr) * 200 + ks * 32 + lq * 8];
#pragma unroll
    for (int jt = 0; jt < 4; ++jt) {
      const bf16x8 vf = *(const bf16x8*)&Vt[(jt * 16 + lr) * 200 + ks * 32 + lq * 8];
      oa[jt] = __builtin_amdgcn_mfma_f32_16x16x32_bf16(pf, vf, oa[jt], 0, 0, 0);
    }
  }
#pragma unroll
  for (int jt = 0; jt < 4; ++jt)
#pragma unroll
    for (int rr = 0; rr < 4; ++rr)
      loc[(size_t)(b * 1024 + i0 + w * 16 + lq * 4 + rr) * 1024 + h * 64 + jt * 16 + lr] =
          oa[jt][rr];
}

// ---------- compressed-KV attention (63 blocks, block-causal), MFMA ----------
// grid (B*H, T/64); block 256.
__global__ __launch_bounds__(256) void comp_attn(const u16* __restrict__ qkv,
                                                 const float* __restrict__ kc,
                                                 const float* __restrict__ vc,
                                                 float* __restrict__ outc) {
  __shared__ u16 Kc[64 * 72];   // [s][d] bf16 (row 63 zero)
  __shared__ u16 Vt[64 * 72];   // [d][s] bf16 (col 63 zero)
  __shared__ u16 Ps[64 * 72];
  const int bh = blockIdx.x;
  const int b = bh >> 4, h = bh & 15;
  const int i0 = blockIdx.y * 64;
  const int tid = threadIdx.x;
  const int lane = tid & 63, w = tid >> 6;
  const int lr = lane & 15, lq = lane >> 4;
  const size_t kbase = (size_t)bh * 63 * 64;

  for (int idx = tid; idx < 63 * 64; idx += 256) {
    const int j = idx >> 6, d = idx & 63;
    Kc[j * 72 + d] = f2bf(kc[kbase + idx]);
    Vt[d * 72 + j] = f2bf(vc[kbase + idx]);
  }
  if (tid < 64) {
    Kc[63 * 72 + tid] = 0;
    Vt[tid * 72 + 63] = 0;
  }
  bf16x8 qf[2];
  {
    const size_t qrow = (size_t)(b * 1024 + i0 + w * 16 + lr) * 3072 + h * 64;
#pragma unroll
    for (int ks = 0; ks < 2; ++ks) qf[ks] = *(const bf16x8*)&qkv[qrow + ks * 32 + lq * 8];
  }
  __syncthreads();

  f32x4 sa[4];
#pragma unroll
  for (int j = 0; j < 4; ++j) sa[j] = (f32x4){0.f, 0.f, 0.f, 0.f};
#pragma unroll
  for (int ks = 0; ks < 2; ++ks)
#pragma unroll
    for (int j = 0; j < 4; ++j) {
      const bf16x8 kf = *(const bf16x8*)&Kc[(j * 16 + lr) * 72 + ks * 32 + lq * 8];
      sa[j] = __builtin_amdgcn_mfma_f32_16x16x32_bf16(qf[ks], kf, sa[j], 0, 0, 0);
    }

  const float NINF = -__builtin_inff();
  float mx[4] = {NINF, NINF, NINF, NINF};
#pragma unroll
  for (int j = 0; j < 4; ++j) {
    const int s = j * 16 + lr;
#pragma unroll
    for (int rr = 0; rr < 4; ++rr) {
      const int i = i0 + w * 16 + lq * 4 + rr;
      const bool valid = (s <= i) && (s < 63);
      const float v = valid ? sa[j][rr] * 0.125f : NINF;
      sa[j][rr] = v;
      mx[rr] = fmaxf(mx[rr], v);
    }
  }
#pragma unroll
  for (int rr = 0; rr < 4; ++rr)
#pragma unroll
    for (int o = 1; o < 16; o <<= 1) mx[rr] = fmaxf(mx[rr], __shfl_xor(mx[rr], o, 64));
  float sum[4] = {0.f, 0.f, 0.f, 0.f};
#pragma unroll
  for (int j = 0; j < 4; ++j)
#pragma unroll
    for (int rr = 0; rr < 4; ++rr) {
      const float p = __expf(sa[j][rr] - mx[rr]);
      sa[j][rr] = p;
      sum[rr] += p;
    }
#pragma unroll
  for (int rr = 0; rr < 4; ++rr) {
#pragma unroll
    for (int o = 1; o < 16; o <<= 1) sum[rr] += __shfl_xor(sum[rr], o, 64);
    sum[rr] = 1.0f / sum[rr];
  }
#pragma unroll
  for (int j = 0; j < 4; ++j)
#pragma unroll
    for (int rr = 0; rr < 4; ++rr)
      Ps[(w * 16 + lq * 4 + rr) * 72 + j * 16 + lr] = f2bf(sa[j][rr] * sum[rr]);
  __syncthreads();

  f32x4 oa[4];
#pragma unroll
  for (int jt = 0; jt < 4; ++jt) oa[jt] = (f32x4){0.f, 0.f, 0.f, 0.f};
#pragma unroll
  for (int ks = 0; ks < 2; ++ks) {
    const bf16x8 pf = *(const bf16x8*)&Ps[(w * 16 + lr) * 72 + ks * 32 + lq * 8];
#pragma unroll
    for (int jt = 0; jt < 4; ++jt) {
      const bf16x8 vf = *(const bf16x8*)&Vt[(jt * 16 + lr) * 72 + ks * 32 + lq * 8];
      oa[jt] = __builtin_amdgcn_mfma_f32_16x16x32_bf16(pf, vf, oa[jt], 0, 0, 0);
    }
  }
#pragma unroll
  for (int jt = 0; jt < 4; ++jt)
#pragma unroll
    for (int rr = 0; rr < 4; ++rr)
      outc[(size_t)(b * 1024 + i0 + w * 16 + lq * 4 + rr) * 1024 + h * 64 + jt * 16 + lr] =
          oa[jt][rr];
}

// ---------- row LayerNorm over C=1024, in-place ----------
__global__ __launch_bounds__(256) void row_ln(float* __restrict__ x,
                                              const float* __restrict__ wt) {
  const int row = blockIdx.x, tid = threadIdx.x;
  const size_t base = (size_t)row * 1024 + tid * 4;
  const f32x4 v = *(const f32x4*)&x[base];
  float s = v[0] + v[1] + v[2] + v[3];
  float s2 = v[0] * v[0] + v[1] * v[1] + v[2] * v[2] + v[3] * v[3];
  s = wredsum(s);
  s2 = wredsum(s2);
  __shared__ float rs[4], rs2[4];
  const int w = tid >> 6, lane = tid & 63;
  if (!lane) {
    rs[w] = s;
    rs2[w] = s2;
  }
  __syncthreads();
  s = rs[0] + rs[1] + rs[2] + rs[3];
  s2 = rs2[0] + rs2[1] + rs2[2] + rs2[3];
  const float m = s * (1.f / 1024.f);
  const float inv = rsqrtf(s2 * (1.f / 1024.f) - m * m + 1e-5f);
  const f32x4 wv = *(const f32x4*)&wt[tid * 4];
  f32x4 o;
#pragma unroll
  for (int k = 0; k < 4; ++k) o[k] = (v[k] - m) * inv * wv[k];
  *(f32x4*)&x[base] = o;
}

// ---------- gating GEMV: hraw[b,o] = feats[b,:] . gate_w1[o,:] ----------
__global__ __launch_bounds__(256) void gate_gemv(const float* __restrict__ locn,
                                                 const float* __restrict__ comp,
                                                 const float* __restrict__ w1,
                                                 float* __restrict__ hraw) {
  __shared__ float fs[2048];
  const int b = blockIdx.x, chunk = blockIdx.y, tid = threadIdx.x;
  const size_t rb = ((size_t)b * 1024 + 1023) * 1024;
  for (int idx = tid; idx < 1024; idx += 256) {
    fs[idx] = locn[rb + idx];
    fs[1024 + idx] = comp[rb + idx];
  }
  __syncthreads();
  const int o = chunk * 256 + tid;
  const float* wr = &w1[(size_t)o * 2048];
  float acc = 0.f;
#pragma unroll 4
  for (int c = 0; c < 2048; c += 4) {
    const f32x4 wv = *(const f32x4*)&wr[c];
    const f32x4 fv = *(const f32x4*)&fs[c];
    acc += fv[0] * wv[0] + fv[1] * wv[1] + fv[2] * wv[2] + fv[3] * wv[3];
  }
  hraw[b * 1024 + o] = acc;
}

// ---------- gating finalize: LN + ReLU + 2-way GEMV + softmax ----------
__global__ __launch_bounds__(256) void gate_fin(const float* __restrict__ hraw,
                                                const float* __restrict__ lnw,
                                                const float* __restrict__ w2,
                                                float* __restrict__ gates) {
  const int b = blockIdx.x, tid = threadIdx.x;
  const f32x4 v = *(const f32x4*)&hraw[(size_t)b * 1024 + tid * 4];
  float s = v[0] + v[1] + v[2] + v[3];
  float s2 = v[0] * v[0] + v[1] * v[1] + v[2] * v[2] + v[3] * v[3];
  s = wredsum(s);
  s2 = wredsum(s2);
  __shared__ float rs[4], rs2[4];
  const int w = tid >> 6, lane = tid & 63;
  if (!lane) {
    rs[w] = s;
    rs2[w] = s2;
  }
  __syncthreads();
  s = rs[0] + rs[1] + rs[2] + rs[3];
  s2 = rs2[0] + rs2[1] + rs2[2] + rs2[3];
  const float m = s * (1.f / 1024.f);
  const float inv = rsqrtf(s2 * (1.f / 1024.f) - m * m + 1e-5f);
  float p0 = 0.f, p1 = 0.f;
#pragma unroll
  for (int k = 0; k < 4; ++k) {
    float hh = (v[k] - m) * inv * lnw[tid * 4 + k];
    hh = fmaxf(hh, 0.f);
    p0 += hh * w2[tid * 4 + k];
    p1 += hh * w2[1024 + tid * 4 + k];
  }
  p0 = wredsum(p0);
  p1 = wredsum(p1);
  __syncthreads();
  if (!lane) {
    rs[w] = p0;
    rs2[w] = p1;
  }
  __syncthreads();
  if (tid == 0) {
    const float l0 = rs[0] + rs[1] + rs[2] + rs[3];
    const float l1 = rs2[0] + rs2[1] + rs2[2] + rs2[3];
    const float mm = fmaxf(l0, l1);
    const float e0 = __expf(l0 - mm), e1 = __expf(l1 - mm);
    const float iv = 1.f / (e0 + e1);
    gates[b * 2] = e0 * iv;
    gates[b * 2 + 1] = e1 * iv;
  }
}

// ---------- combine + cast to bf16 ----------
__global__ __launch_bounds__(256) void combine_cast(const float* __restrict__ locn,
                                                    const float* __restrict__ comp,
                                                    const float* __restrict__ gates,
                                                    u16* __restrict__ outb) {
  const size_t idx = ((size_t)blockIdx.x * 256 + threadIdx.x) * 4;
  const int b = (int)(idx >> 20);
  const float g0 = gates[2 * b], g1 = gates[2 * b + 1];
  const f32x4 a = *(const f32x4*)&locn[idx];
  const f32x4 c = *(const f32x4*)&comp[idx];
  u32x2 r;
  r[0] = (u32)f2bf(g0 * a[0] + g1 * c[0]) | ((u32)f2bf(g0 * a[1] + g1 * c[1]) << 16);
  r[1] = (u32)f2bf(g0 * a[2] + g1 * c[2]) | ((u32)f2bf(g0 * a[3] + g1 * c[3]) << 16);
  *(u32x2*)&outb[idx] = r;
}

// ---------- launcher ----------
extern "C" void kernel_launch(void* const* d_in, const int* in_sizes, int n_in,
                              void* d_out, int out_size, void* d_ws, size_t ws_size,
                              hipStream_t stream) {
  const float* x = (const float*)d_in[0];
  const float* c_attn_w = (const float*)d_in[1];
  const float* conv_w = (const float*)d_in[2];
  const float* ln_comp_w = (const float*)d_in[3];
  const float* ln_local_w = (const float*)d_in[4];
  const float* gate_w1 = (const float*)d_in[5];
  const float* gate_ln_w = (const float*)d_in[6];
  const float* gate_w2 = (const float*)d_in[7];
  const float* c_proj_w = (const float*)d_in[8];
  float* y = (float*)d_out;

  char* ws = (char*)d_ws;
  size_t off = 0;
  auto alloc = [&](size_t bytes) -> void* {
    void* p = ws + off;
    off += (bytes + 255) & ~(size_t)255;
    return p;
  };
  u16* qkvb = (u16*)alloc((size_t)8192 * 3072 * 2);
  u16* xb = (u16*)alloc((size_t)8192 * 1024 * 2);
  u16* wab = (u16*)alloc((size_t)3072 * 1024 * 2);
  u16* wpb = (u16*)alloc((size_t)1024 * 1024 * 2);
  u16* wcb = (u16*)alloc((size_t)64 * 2048 * 2);
  float* kc = (float*)alloc((size_t)8064 * 64 * 4);
  float* vc = (float*)alloc((size_t)8064 * 64 * 4);
  float* locn = (float*)alloc((size_t)8192 * 1024 * 4);
  float* comp = (float*)alloc((size_t)8192 * 1024 * 4);
  float* hraw = (float*)alloc((size_t)8192 * 4);
  float* gates = (float*)alloc(64);
  u16* combb = (u16*)alloc((size_t)8192 * 1024 * 2);

  cast_f32_bf16<<<8192, 256, 0, stream>>>(x, xb);
  cast_f32_bf16<<<3072, 256, 0, stream>>>(c_attn_w, wab);
  cast_f32_bf16<<<1024, 256, 0, stream>>>(c_proj_w, wpb);
  cast_convw<<<512, 256, 0, stream>>>(conv_w, wcb);

  gemm_bt<1><<<dim3(64, 24), 256, 0, stream>>>(xb, wab, qkvb, 8192, 3072, 1024);

  compress_kernel<<<dim3(63, 2), 256, 0, stream>>>(qkvb, wcb, ln_comp_w, kc, vc);

  local_attn<<<dim3(128, 16), 256, 0, stream>>>(qkvb, locn);
  comp_attn<<<dim3(128, 16), 256, 0, stream>>>(qkvb, kc, vc, comp);

  row_ln<<<8192, 256, 0, stream>>>(locn, ln_local_w);

  gate_gemv<<<dim3(8, 4), 256, 0, stream>>>(locn, comp, gate_w1, hraw);
  gate_fin<<<8, 256, 0, stream>>>(hraw, gate_ln_w, gate_w2, gates);

  combine_cast<<<8192, 256, 0, stream>>>(locn, comp, gates, combb);

  gemm_bt<0><<<dim3(64, 8), 256, 0, stream>>>(combb, wpb, y, 8192, 1024, 1024);
}

// Round 3
// 333.024 us; speedup vs baseline: 2.8732x; 1.2256x over previous
//
#include <hip/hip_runtime.h>
#include <cstdint>
#include <cmath>
#include <cstddef>

typedef unsigned int u32;
typedef unsigned short u16;
typedef __bf16 bf16x8 __attribute__((ext_vector_type(8)));
typedef float f32x4 __attribute__((ext_vector_type(4)));
typedef u32 u32x4 __attribute__((ext_vector_type(4)));
typedef u32 u32x2 __attribute__((ext_vector_type(2)));

#define DEV static __device__ __forceinline__

// ---------- helpers ----------
DEV u16 f2bf(float f) {               // RNE fp32 -> bf16
  u32 u = __float_as_uint(f);
  u += 0x7fffu + ((u >> 16) & 1u);
  return (u16)(u >> 16);
}
DEV float wredsum(float v) {
#pragma unroll
  for (int o = 32; o; o >>= 1) v += __shfl_xor(v, o, 64);
  return v;
}

// async global->LDS, 16B per lane. LDS dest is wave-uniform base + lane*16.
DEV void gload_lds16(const u16* g, u16* lds_base) {
  __builtin_amdgcn_global_load_lds((const __attribute__((address_space(1))) void*)g,
                                   (__attribute__((address_space(3))) void*)lds_base,
                                   16, 0, 0);
}

// ---------- generic fp32 -> bf16 cast (n multiple of 1024) ----------
__global__ __launch_bounds__(256) void cast_f32_bf16(const float* __restrict__ in,
                                                     u16* __restrict__ out) {
  const size_t idx = ((size_t)blockIdx.x * 256 + threadIdx.x) * 4;
  const f32x4 v = *(const f32x4*)&in[idx];
  u32x2 r;
  r[0] = (u32)f2bf(v[0]) | ((u32)f2bf(v[1]) << 16);
  r[1] = (u32)f2bf(v[2]) | ((u32)f2bf(v[3]) << 16);
  *(u32x2*)&out[idx] = r;
}

// conv_w [64][64][32] (o,i,kk) fp32 -> Wc [64][2048] bf16 with Wc[o][kk*64+i]
__global__ __launch_bounds__(256) void cast_convw(const float* __restrict__ cw,
                                                  u16* __restrict__ wc) {
  const int idx = blockIdx.x * 256 + threadIdx.x;  // 131072 total
  const int o = idx >> 11;
  const int rest = idx & 2047;
  const int i = rest >> 5;
  const int kk = rest & 31;
  wc[(o << 11) + (kk << 6) + i] = f2bf(cw[idx]);
}

// ---------- MFMA GEMM: out[M,N] = A[M,K](bf16) * B[N,K](bf16)^T ----------
// 128x128 tile, BK=32, 256 threads (4 waves, 2x2 wave grid of 64x64)
// Staging via global_load_lds width=16 (m97 pattern).
template <int OUT_BF16>
__global__ __launch_bounds__(256) void gemm_bt(const u16* __restrict__ A,
                                               const u16* __restrict__ Bm,
                                               void* __restrict__ out,
                                               int M, int N, int K) {
  __shared__ u16 As[128 * 32];
  __shared__ u16 Bs[128 * 32];
  const int tid = threadIdx.x;
  const int lane = tid & 63;
  const int w = tid >> 6;
  const int row0 = blockIdx.x * 128;
  const int col0 = blockIdx.y * 128;
  const int wm = (w >> 1) * 64, wn = (w & 1) * 64;
  const int lr = lane & 15, lq = lane >> 4;
  const int srow = lane >> 2;          // 0..15 row within 16-row chunk
  const int scol = (lane & 3) * 8;     // 0,8,16,24

  f32x4 acc[4][4] = {};

  for (int k0 = 0; k0 < K; k0 += 32) {
    __syncthreads();
#pragma unroll
    for (int p = 0; p < 2; ++p) {
      const int base_r = p * 64 + w * 16;   // wave-uniform
      gload_lds16(&A[(size_t)(row0 + base_r + srow) * K + k0 + scol], &As[base_r * 32]);
      gload_lds16(&Bm[(size_t)(col0 + base_r + srow) * K + k0 + scol], &Bs[base_r * 32]);
    }
    __syncthreads();
    bf16x8 af[4], bfr[4];
#pragma unroll
    for (int i = 0; i < 4; ++i) {
      af[i] = *(const bf16x8*)&As[(wm + i * 16 + lr) * 32 + lq * 8];
      bfr[i] = *(const bf16x8*)&Bs[(wn + i * 16 + lr) * 32 + lq * 8];
    }
#pragma unroll
    for (int i = 0; i < 4; ++i)
#pragma unroll
      for (int j = 0; j < 4; ++j)
        acc[i][j] = __builtin_amdgcn_mfma_f32_16x16x32_bf16(af[i], bfr[j], acc[i][j], 0, 0, 0);
  }
  // D layout: col = lane&15, row = (lane>>4)*4 + rr  [m89-verified]
#pragma unroll
  for (int i = 0; i < 4; ++i)
#pragma unroll
    for (int j = 0; j < 4; ++j)
#pragma unroll
      for (int rr = 0; rr < 4; ++rr) {
        const int gr = row0 + wm + i * 16 + lq * 4 + rr;
        const int gc = col0 + wn + j * 16 + lr;
        const float v = acc[i][j][rr];
        if (OUT_BF16)
          ((u16*)out)[(size_t)gr * N + gc] = f2bf(v);
        else
          ((float*)out)[(size_t)gr * N + gc] = v;
      }
}

// ---------- compression: conv(K=32,stride16) as GEMM + LN(64) + exact GELU ----------
// M = (B*H)*63 = 8064 rows, N = 64, K = 2048.  grid (63, 2): y=0 -> k, y=1 -> v
__global__ __launch_bounds__(256) void compress_kernel(const u16* __restrict__ qkv,
                                                       const u16* __restrict__ Wc,
                                                       const float* __restrict__ ln_w,
                                                       float* __restrict__ out_k,
                                                       float* __restrict__ out_v) {
  __shared__ u16 As[128 * 32];
  __shared__ u16 Bs[64 * 32];
  __shared__ float Cs[128][65];
  const int srcoff = 1024 + (int)blockIdx.y * 1024;
  float* outp = blockIdx.y ? out_v : out_k;
  const int tid = threadIdx.x;
  const int lane = tid & 63;
  const int w = tid >> 6;
  const int r0 = blockIdx.x * 128;
  const int lr = lane & 15, lq = lane >> 4;

  size_t rowbase[2];
#pragma unroll
  for (int p = 0; p < 2; ++p) {
    const int idx = p * 256 + tid;
    const int r = idx >> 2, c = (idx & 3) * 8;
    const int gr = r0 + r;
    const int bh = gr / 63;
    const int nb = gr - bh * 63;
    const int b = bh >> 4, h = bh & 15;
    rowbase[p] = (size_t)(b * 1024 + nb * 16) * 3072 + srcoff + h * 64 + c;
  }
  const int brow = tid >> 2, bcol = (tid & 3) * 8;

  f32x4 acc[2][4] = {};
  for (int k0 = 0; k0 < 2048; k0 += 32) {
    const int kk = k0 >> 6;
    const int i0 = k0 & 63;  // 0 or 32
    __syncthreads();
#pragma unroll
    for (int p = 0; p < 2; ++p) {
      const int idx = p * 256 + tid;
      const int r = idx >> 2, c = (idx & 3) * 8;
      *(u32x4*)&As[r * 32 + c] = *(const u32x4*)&qkv[rowbase[p] + (size_t)kk * 3072 + i0];
    }
    *(u32x4*)&Bs[brow * 32 + bcol] = *(const u32x4*)&Wc[(size_t)brow * 2048 + k0 + bcol];
    __syncthreads();
    bf16x8 af[2], bfr[4];
#pragma unroll
    for (int i = 0; i < 2; ++i) af[i] = *(const bf16x8*)&As[(w * 32 + i * 16 + lr) * 32 + lq * 8];
#pragma unroll
    for (int j = 0; j < 4; ++j) bfr[j] = *(const bf16x8*)&Bs[(j * 16 + lr) * 32 + lq * 8];
#pragma unroll
    for (int i = 0; i < 2; ++i)
#pragma unroll
      for (int j = 0; j < 4; ++j)
        acc[i][j] = __builtin_amdgcn_mfma_f32_16x16x32_bf16(af[i], bfr[j], acc[i][j], 0, 0, 0);
  }
  __syncthreads();
#pragma unroll
  for (int i = 0; i < 2; ++i)
#pragma unroll
    for (int j = 0; j < 4; ++j)
#pragma unroll
      for (int rr = 0; rr < 4; ++rr)
        Cs[w * 32 + i * 16 + lq * 4 + rr][j * 16 + lr] = acc[i][j][rr];
  __syncthreads();
  if (tid < 128) {
    const int r = tid;
    float s = 0.f, s2 = 0.f;
#pragma unroll 8
    for (int d = 0; d < 64; ++d) {
      const float x = Cs[r][d];
      s += x;
      s2 += x * x;
    }
    const float m = s * (1.f / 64.f);
    const float inv = rsqrtf(s2 * (1.f / 64.f) - m * m + 1e-5f);
    const size_t gr = (size_t)(r0 + r) * 64;
#pragma unroll 8
    for (int d = 0; d < 64; ++d) {
      const float z = (Cs[r][d] - m) * inv * ln_w[d];
      outp[gr + d] = 0.5f * z * (1.f + erff(z * 0.70710678118f));
    }
  }
}

// ---------- local banded attention (window 129), MFMA flash-style ----------
__global__ __launch_bounds__(256) void local_attn(const u16* __restrict__ qkv,
                                                  float* __restrict__ loc) {
  __shared__ __align__(16) char smem[53248];
  u16* Ks = (u16*)smem;            // [192][72] bf16, phase 1
  u16* Vt = (u16*)smem;            // [64][200] bf16, phase 2 (overlaps Ks)
  u16* Ps = (u16*)(smem + 27648);  // [64][200] bf16, phase 2
  const int bh = blockIdx.x;
  const int b = bh >> 4, h = bh & 15;
  const int i0 = blockIdx.y * 64;
  const int jbase = i0 - 128;
  const int tid = threadIdx.x;
  const int lane = tid & 63, w = tid >> 6;
  const int lr = lane & 15, lq = lane >> 4;

  u32x4 vreg[6];
#pragma unroll
  for (int c = 0; c < 6; ++c) {
    const int lin = c * 256 + tid;
    const int s = lin >> 3, d0 = (lin & 7) * 8;
    const int j = jbase + s;
    u32x4 kval = {0, 0, 0, 0}, vval = {0, 0, 0, 0};
    if (j >= 0) {
      const size_t ro = (size_t)(b * 1024 + j) * 3072 + h * 64 + d0;
      kval = *(const u32x4*)&qkv[ro + 1024];
      vval = *(const u32x4*)&qkv[ro + 2048];
    }
    vreg[c] = vval;
    *(u32x4*)&Ks[s * 72 + d0] = kval;
  }
  bf16x8 qf[2];
  {
    const size_t qrow = (size_t)(b * 1024 + i0 + w * 16 + lr) * 3072 + h * 64;
#pragma unroll
    for (int ks = 0; ks < 2; ++ks) qf[ks] = *(const bf16x8*)&qkv[qrow + ks * 32 + lq * 8];
  }
  __syncthreads();

  f32x4 sa[12];
#pragma unroll
  for (int j = 0; j < 12; ++j) sa[j] = (f32x4){0.f, 0.f, 0.f, 0.f};
#pragma unroll
  for (int ks = 0; ks < 2; ++ks)
#pragma unroll
    for (int j = 0; j < 12; ++j) {
      const bf16x8 kf = *(const bf16x8*)&Ks[(j * 16 + lr) * 72 + ks * 32 + lq * 8];
      sa[j] = __builtin_amdgcn_mfma_f32_16x16x32_bf16(qf[ks], kf, sa[j], 0, 0, 0);
    }

  const float NINF = -__builtin_inff();
  float mx[4] = {NINF, NINF, NINF, NINF};
#pragma unroll
  for (int j = 0; j < 12; ++j) {
    const int s = j * 16 + lr;
#pragma unroll
    for (int rr = 0; rr < 4; ++rr) {
      const int qi = w * 16 + lq * 4 + rr;
      const bool valid = (jbase + s >= 0) && (s >= qi) && (s <= qi + 128);
      const float v = valid ? sa[j][rr] * 0.125f : NINF;
      sa[j][rr] = v;
      mx[rr] = fmaxf(mx[rr], v);
    }
  }
#pragma unroll
  for (int rr = 0; rr < 4; ++rr)
#pragma unroll
    for (int o = 1; o < 16; o <<= 1) mx[rr] = fmaxf(mx[rr], __shfl_xor(mx[rr], o, 64));
  float sum[4] = {0.f, 0.f, 0.f, 0.f};
#pragma unroll
  for (int j = 0; j < 12; ++j)
#pragma unroll
    for (int rr = 0; rr < 4; ++rr) {
      const float p = __expf(sa[j][rr] - mx[rr]);
      sa[j][rr] = p;
      sum[rr] += p;
    }
#pragma unroll
  for (int rr = 0; rr < 4; ++rr) {
#pragma unroll
    for (int o = 1; o < 16; o <<= 1) sum[rr] += __shfl_xor(sum[rr], o, 64);
    sum[rr] = 1.0f / sum[rr];
  }
  __syncthreads();  // all waves done reading Ks before Vt overlays it

#pragma unroll
  for (int j = 0; j < 12; ++j)
#pragma unroll
    for (int rr = 0; rr < 4; ++rr)
      Ps[(w * 16 + lq * 4 + rr) * 200 + j * 16 + lr] = f2bf(sa[j][rr] * sum[rr]);
#pragma unroll
  for (int c = 0; c < 6; ++c) {
    const int lin = c * 256 + tid;
    const int s = lin >> 3, d0 = (lin & 7) * 8;
    const u32x4 val = vreg[c];
#pragma unroll
    for (int q = 0; q < 4; ++q) {
      Vt[(d0 + 2 * q) * 200 + s] = (u16)(val[q] & 0xffffu);
      Vt[(d0 + 2 * q + 1) * 200 + s] = (u16)(val[q] >> 16);
    }
  }
  __syncthreads();

  f32x4 oa[4];
#pragma unroll
  for (int jt = 0; jt < 4; ++jt) oa[jt] = (f32x4){0.f, 0.f, 0.f, 0.f};
#pragma unroll
  for (int ks = 0; ks < 6; ++ks) {
    const bf16x8 pf = *(const bf16x8*)&Ps[(w * 16 + lr) * 200 + ks * 32 + lq * 8];
#pragma unroll
    for (int jt = 0; jt < 4; ++jt) {
      const bf16x8 vf = *(const bf16x8*)&Vt[(jt * 16 + lr) * 200 + ks * 32 + lq * 8];
      oa[jt] = __builtin_amdgcn_mfma_f32_16x16x32_bf16(pf, vf, oa[jt], 0, 0, 0);
    }
  }
#pragma unroll
  for (int jt = 0; jt < 4; ++jt)
#pragma unroll
    for (int rr = 0; rr < 4; ++rr)
      loc[(size_t)(b * 1024 + i0 + w * 16 + lq * 4 + rr) * 1024 + h * 64 + jt * 16 + lr] =
          oa[jt][rr];
}

// ---------- compressed-KV attention (63 blocks, block-causal), MFMA ----------
__global__ __launch_bounds__(256) void comp_attn(const u16* __restrict__ qkv,
                                                 const float* __restrict__ kc,
                                                 const float* __restrict__ vc,
                                                 float* __restrict__ outc) {
  __shared__ u16 Kc[64 * 72];
  __shared__ u16 Vt[64 * 72];
  __shared__ u16 Ps[64 * 72];
  const int bh = blockIdx.x;
  const int b = bh >> 4, h = bh & 15;
  const int i0 = blockIdx.y * 64;
  const int tid = threadIdx.x;
  const int lane = tid & 63, w = tid >> 6;
  const int lr = lane & 15, lq = lane >> 4;
  const size_t kbase = (size_t)bh * 63 * 64;

  for (int idx = tid; idx < 63 * 64; idx += 256) {
    const int j = idx >> 6, d = idx & 63;
    Kc[j * 72 + d] = f2bf(kc[kbase + idx]);
    Vt[d * 72 + j] = f2bf(vc[kbase + idx]);
  }
  if (tid < 64) {
    Kc[63 * 72 + tid] = 0;
    Vt[tid * 72 + 63] = 0;
  }
  bf16x8 qf[2];
  {
    const size_t qrow = (size_t)(b * 1024 + i0 + w * 16 + lr) * 3072 + h * 64;
#pragma unroll
    for (int ks = 0; ks < 2; ++ks) qf[ks] = *(const bf16x8*)&qkv[qrow + ks * 32 + lq * 8];
  }
  __syncthreads();

  f32x4 sa[4];
#pragma unroll
  for (int j = 0; j < 4; ++j) sa[j] = (f32x4){0.f, 0.f, 0.f, 0.f};
#pragma unroll
  for (int ks = 0; ks < 2; ++ks)
#pragma unroll
    for (int j = 0; j < 4; ++j) {
      const bf16x8 kf = *(const bf16x8*)&Kc[(j * 16 + lr) * 72 + ks * 32 + lq * 8];
      sa[j] = __builtin_amdgcn_mfma_f32_16x16x32_bf16(qf[ks], kf, sa[j], 0, 0, 0);
    }

  const float NINF = -__builtin_inff();
  float mx[4] = {NINF, NINF, NINF, NINF};
#pragma unroll
  for (int j = 0; j < 4; ++j) {
    const int s = j * 16 + lr;
#pragma unroll
    for (int rr = 0; rr < 4; ++rr) {
      const int i = i0 + w * 16 + lq * 4 + rr;
      const bool valid = (s <= i) && (s < 63);
      const float v = valid ? sa[j][rr] * 0.125f : NINF;
      sa[j][rr] = v;
      mx[rr] = fmaxf(mx[rr], v);
    }
  }
#pragma unroll
  for (int rr = 0; rr < 4; ++rr)
#pragma unroll
    for (int o = 1; o < 16; o <<= 1) mx[rr] = fmaxf(mx[rr], __shfl_xor(mx[rr], o, 64));
  float sum[4] = {0.f, 0.f, 0.f, 0.f};
#pragma unroll
  for (int j = 0; j < 4; ++j)
#pragma unroll
    for (int rr = 0; rr < 4; ++rr) {
      const float p = __expf(sa[j][rr] - mx[rr]);
      sa[j][rr] = p;
      sum[rr] += p;
    }
#pragma unroll
  for (int rr = 0; rr < 4; ++rr) {
#pragma unroll
    for (int o = 1; o < 16; o <<= 1) sum[rr] += __shfl_xor(sum[rr], o, 64);
    sum[rr] = 1.0f / sum[rr];
  }
#pragma unroll
  for (int j = 0; j < 4; ++j)
#pragma unroll
    for (int rr = 0; rr < 4; ++rr)
      Ps[(w * 16 + lq * 4 + rr) * 72 + j * 16 + lr] = f2bf(sa[j][rr] * sum[rr]);
  __syncthreads();

  f32x4 oa[4];
#pragma unroll
  for (int jt = 0; jt < 4; ++jt) oa[jt] = (f32x4){0.f, 0.f, 0.f, 0.f};
#pragma unroll
  for (int ks = 0; ks < 2; ++ks) {
    const bf16x8 pf = *(const bf16x8*)&Ps[(w * 16 + lr) * 72 + ks * 32 + lq * 8];
#pragma unroll
    for (int jt = 0; jt < 4; ++jt) {
      const bf16x8 vf = *(const bf16x8*)&Vt[(jt * 16 + lr) * 72 + ks * 32 + lq * 8];
      oa[jt] = __builtin_amdgcn_mfma_f32_16x16x32_bf16(pf, vf, oa[jt], 0, 0, 0);
    }
  }
#pragma unroll
  for (int jt = 0; jt < 4; ++jt)
#pragma unroll
    for (int rr = 0; rr < 4; ++rr)
      outc[(size_t)(b * 1024 + i0 + w * 16 + lq * 4 + rr) * 1024 + h * 64 + jt * 16 + lr] =
          oa[jt][rr];
}

// ---------- LN of the 8 last-token local rows + pack feats[8][2048] ----------
__global__ __launch_bounds__(256) void ln_feats(const float* __restrict__ locn,
                                                const float* __restrict__ comp,
                                                const float* __restrict__ lnw,
                                                float* __restrict__ feats) {
  const int b = blockIdx.x, tid = threadIdx.x;
  const size_t base = ((size_t)b * 1024 + 1023) * 1024 + tid * 4;
  const f32x4 v = *(const f32x4*)&locn[base];
  float s = v[0] + v[1] + v[2] + v[3];
  float s2 = v[0] * v[0] + v[1] * v[1] + v[2] * v[2] + v[3] * v[3];
  s = wredsum(s);
  s2 = wredsum(s2);
  __shared__ float rs[4], rs2[4];
  const int w = tid >> 6, lane = tid & 63;
  if (!lane) { rs[w] = s; rs2[w] = s2; }
  __syncthreads();
  s = rs[0] + rs[1] + rs[2] + rs[3];
  s2 = rs2[0] + rs2[1] + rs2[2] + rs2[3];
  const float m = s * (1.f / 1024.f);
  const float inv = rsqrtf(s2 * (1.f / 1024.f) - m * m + 1e-5f);
  const f32x4 wv = *(const f32x4*)&lnw[tid * 4];
  f32x4 o;
#pragma unroll
  for (int k = 0; k < 4; ++k) o[k] = (v[k] - m) * inv * wv[k];
  *(f32x4*)&feats[b * 2048 + tid * 4] = o;
  *(f32x4*)&feats[b * 2048 + 1024 + tid * 4] = *(const f32x4*)&comp[base];
}

// ---------- gating GEMV: hraw[b,o] = feats[b,:] . w1[o,:] ----------
// grid(256); 4 waves/block, one w1 row per wave, coalesced 16B/lane reads.
__global__ __launch_bounds__(256) void gate_gemv(const float* __restrict__ feats,
                                                 const float* __restrict__ w1,
                                                 float* __restrict__ hraw) {
  const int o = blockIdx.x * 4 + (threadIdx.x >> 6);
  const int lane = threadIdx.x & 63;
  const float* wr = &w1[(size_t)o * 2048];
  float acc[8] = {};
#pragma unroll
  for (int it = 0; it < 8; ++it) {
    const int c = (it * 64 + lane) * 4;
    const f32x4 wv = *(const f32x4*)&wr[c];
#pragma unroll
    for (int b = 0; b < 8; ++b) {
      const f32x4 fv = *(const f32x4*)&feats[b * 2048 + c];
      acc[b] += fv[0] * wv[0] + fv[1] * wv[1] + fv[2] * wv[2] + fv[3] * wv[3];
    }
  }
#pragma unroll
  for (int b = 0; b < 8; ++b) acc[b] = wredsum(acc[b]);
  if (lane == 0) {
#pragma unroll
    for (int b = 0; b < 8; ++b) hraw[b * 1024 + o] = acc[b];
  }
}

// ---------- gating finalize: LN + ReLU + 2-way GEMV + softmax ----------
__global__ __launch_bounds__(256) void gate_fin(const float* __restrict__ hraw,
                                                const float* __restrict__ lnw,
                                                const float* __restrict__ w2,
                                                float* __restrict__ gates) {
  const int b = blockIdx.x, tid = threadIdx.x;
  const f32x4 v = *(const f32x4*)&hraw[(size_t)b * 1024 + tid * 4];
  float s = v[0] + v[1] + v[2] + v[3];
  float s2 = v[0] * v[0] + v[1] * v[1] + v[2] * v[2] + v[3] * v[3];
  s = wredsum(s);
  s2 = wredsum(s2);
  __shared__ float rs[4], rs2[4];
  const int w = tid >> 6, lane = tid & 63;
  if (!lane) { rs[w] = s; rs2[w] = s2; }
  __syncthreads();
  s = rs[0] + rs[1] + rs[2] + rs[3];
  s2 = rs2[0] + rs2[1] + rs2[2] + rs2[3];
  const float m = s * (1.f / 1024.f);
  const float inv = rsqrtf(s2 * (1.f / 1024.f) - m * m + 1e-5f);
  float p0 = 0.f, p1 = 0.f;
#pragma unroll
  for (int k = 0; k < 4; ++k) {
    float hh = (v[k] - m) * inv * lnw[tid * 4 + k];
    hh = fmaxf(hh, 0.f);
    p0 += hh * w2[tid * 4 + k];
    p1 += hh * w2[1024 + tid * 4 + k];
  }
  p0 = wredsum(p0);
  p1 = wredsum(p1);
  __syncthreads();
  if (!lane) { rs[w] = p0; rs2[w] = p1; }
  __syncthreads();
  if (tid == 0) {
    const float l0 = rs[0] + rs[1] + rs[2] + rs[3];
    const float l1 = rs2[0] + rs2[1] + rs2[2] + rs2[3];
    const float mm = fmaxf(l0, l1);
    const float e0 = __expf(l0 - mm), e1 = __expf(l1 - mm);
    const float iv = 1.f / (e0 + e1);
    gates[b * 2] = e0 * iv;
    gates[b * 2 + 1] = e1 * iv;
  }
}

// ---------- fused: per-row LN of local_out + gate-combine + bf16 cast ----------
__global__ __launch_bounds__(256) void combine_ln_cast(const float* __restrict__ locn,
                                                       const float* __restrict__ comp,
                                                       const float* __restrict__ lnw,
                                                       const float* __restrict__ gates,
                                                       u16* __restrict__ outb) {
  const int row = blockIdx.x, tid = threadIdx.x;
  const size_t base = (size_t)row * 1024 + tid * 4;
  const f32x4 v = *(const f32x4*)&locn[base];
  float s = v[0] + v[1] + v[2] + v[3];
  float s2 = v[0] * v[0] + v[1] * v[1] + v[2] * v[2] + v[3] * v[3];
  s = wredsum(s);
  s2 = wredsum(s2);
  __shared__ float rs[4], rs2[4];
  const int w = tid >> 6, lane = tid & 63;
  if (!lane) { rs[w] = s; rs2[w] = s2; }
  __syncthreads();
  s = rs[0] + rs[1] + rs[2] + rs[3];
  s2 = rs2[0] + rs2[1] + rs2[2] + rs2[3];
  const float m = s * (1.f / 1024.f);
  const float inv = rsqrtf(s2 * (1.f / 1024.f) - m * m + 1e-5f);
  const int b = row >> 10;
  const float g0 = gates[2 * b], g1 = gates[2 * b + 1];
  const f32x4 wv = *(const f32x4*)&lnw[tid * 4];
  const f32x4 c = *(const f32x4*)&comp[base];
  float ov[4];
#pragma unroll
  for (int k = 0; k < 4; ++k) ov[k] = g0 * ((v[k] - m) * inv * wv[k]) + g1 * c[k];
  u32x2 r;
  r[0] = (u32)f2bf(ov[0]) | ((u32)f2bf(ov[1]) << 16);
  r[1] = (u32)f2bf(ov[2]) | ((u32)f2bf(ov[3]) << 16);
  *(u32x2*)&outb[base] = r;
}

// ---------- launcher ----------
extern "C" void kernel_launch(void* const* d_in, const int* in_sizes, int n_in,
                              void* d_out, int out_size, void* d_ws, size_t ws_size,
                              hipStream_t stream) {
  const float* x = (const float*)d_in[0];
  const float* c_attn_w = (const float*)d_in[1];
  const float* conv_w = (const float*)d_in[2];
  const float* ln_comp_w = (const float*)d_in[3];
  const float* ln_local_w = (const float*)d_in[4];
  const float* gate_w1 = (const float*)d_in[5];
  const float* gate_ln_w = (const float*)d_in[6];
  const float* gate_w2 = (const float*)d_in[7];
  const float* c_proj_w = (const float*)d_in[8];
  float* y = (float*)d_out;

  char* ws = (char*)d_ws;
  size_t off = 0;
  auto alloc = [&](size_t bytes) -> void* {
    void* p = ws + off;
    off += (bytes + 255) & ~(size_t)255;
    return p;
  };
  u16* qkvb = (u16*)alloc((size_t)8192 * 3072 * 2);
  u16* xb = (u16*)alloc((size_t)8192 * 1024 * 2);
  u16* wab = (u16*)alloc((size_t)3072 * 1024 * 2);
  u16* wpb = (u16*)alloc((size_t)1024 * 1024 * 2);
  u16* wcb = (u16*)alloc((size_t)64 * 2048 * 2);
  float* kc = (float*)alloc((size_t)8064 * 64 * 4);
  float* vc = (float*)alloc((size_t)8064 * 64 * 4);
  float* locn = (float*)alloc((size_t)8192 * 1024 * 4);   // raw local_out
  float* comp = (float*)alloc((size_t)8192 * 1024 * 4);
  float* feats = (float*)alloc((size_t)8 * 2048 * 4);
  float* hraw = (float*)alloc((size_t)8192 * 4);
  float* gates = (float*)alloc(64);
  u16* combb = (u16*)alloc((size_t)8192 * 1024 * 2);

  cast_f32_bf16<<<8192, 256, 0, stream>>>(x, xb);
  cast_f32_bf16<<<3072, 256, 0, stream>>>(c_attn_w, wab);
  cast_f32_bf16<<<1024, 256, 0, stream>>>(c_proj_w, wpb);
  cast_convw<<<512, 256, 0, stream>>>(conv_w, wcb);

  gemm_bt<1><<<dim3(64, 24), 256, 0, stream>>>(xb, wab, qkvb, 8192, 3072, 1024);

  compress_kernel<<<dim3(63, 2), 256, 0, stream>>>(qkvb, wcb, ln_comp_w, kc, vc);

  local_attn<<<dim3(128, 16), 256, 0, stream>>>(qkvb, locn);
  comp_attn<<<dim3(128, 16), 256, 0, stream>>>(qkvb, kc, vc, comp);

  ln_feats<<<8, 256, 0, stream>>>(locn, comp, ln_local_w, feats);
  gate_gemv<<<256, 256, 0, stream>>>(feats, gate_w1, hraw);
  gate_fin<<<8, 256, 0, stream>>>(hraw, gate_ln_w, gate_w2, gates);

  combine_ln_cast<<<8192, 256, 0, stream>>>(locn, comp, ln_local_w, gates, combb);

  gemm_bt<0><<<dim3(64, 8), 256, 0, stream>>>(combb, wpb, y, 8192, 1024, 1024);
}

// Round 4
// 313.989 us; speedup vs baseline: 3.0474x; 1.0606x over previous
//
#include <hip/hip_runtime.h>
#include <cstdint>
#include <cmath>
#include <cstddef>

typedef unsigned int u32;
typedef unsigned short u16;
typedef __bf16 bf16x8 __attribute__((ext_vector_type(8)));
typedef float f32x4 __attribute__((ext_vector_type(4)));
typedef u32 u32x4 __attribute__((ext_vector_type(4)));
typedef u32 u32x2 __attribute__((ext_vector_type(2)));

#define DEV static __device__ __forceinline__

// ---------- helpers ----------
DEV float bflo(u32 u) { return __uint_as_float(u << 16); }
DEV float bfhi(u32 u) { return __uint_as_float(u & 0xffff0000u); }
DEV u16 f2bf(float f) {               // RNE fp32 -> bf16
  u32 u = __float_as_uint(f);
  u += 0x7fffu + ((u >> 16) & 1u);
  return (u16)(u >> 16);
}
DEV f32x4 unpack_bf4(u32x2 r) {
  return (f32x4){bflo(r[0]), bfhi(r[0]), bflo(r[1]), bfhi(r[1])};
}
DEV float wredsum(float v) {
#pragma unroll
  for (int o = 32; o; o >>= 1) v += __shfl_xor(v, o, 64);
  return v;
}

// async global->LDS, 16B per lane. LDS dest is wave-uniform base + lane*16.
DEV void gload_lds16(const u16* g, u16* lds_base) {
  __builtin_amdgcn_global_load_lds((const __attribute__((address_space(1))) void*)g,
                                   (__attribute__((address_space(3))) void*)lds_base,
                                   16, 0, 0);
}

// ---------- fused casts + workspace pad zeroing ----------
// blocks 0..8191: x; 8192..11263: c_attn_w; 11264..12287: c_proj_w;
// 12288..12799: conv_w repack; 12800: zero kcb row63 / vcb col63 pads.
__global__ __launch_bounds__(256) void fused_cast(const float* __restrict__ x,
                                                  const float* __restrict__ aw,
                                                  const float* __restrict__ pw,
                                                  const float* __restrict__ cw,
                                                  u16* __restrict__ xb,
                                                  u16* __restrict__ wab,
                                                  u16* __restrict__ wpb,
                                                  u16* __restrict__ wcb,
                                                  u16* __restrict__ kcb,
                                                  u16* __restrict__ vcb) {
  const int blk = blockIdx.x;
  if (blk < 12288) {
    const float* src;
    u16* dst;
    int base;
    if (blk < 8192) { src = x; dst = xb; base = blk; }
    else if (blk < 11264) { src = aw; dst = wab; base = blk - 8192; }
    else { src = pw; dst = wpb; base = blk - 11264; }
    const size_t idx = ((size_t)base * 256 + threadIdx.x) * 4;
    const f32x4 v = *(const f32x4*)&src[idx];
    u32x2 r;
    r[0] = (u32)f2bf(v[0]) | ((u32)f2bf(v[1]) << 16);
    r[1] = (u32)f2bf(v[2]) | ((u32)f2bf(v[3]) << 16);
    *(u32x2*)&dst[idx] = r;
  } else if (blk < 12800) {
    // conv_w [64][64][32] (o,i,kk) fp32 -> Wc[o][kk*64+i] bf16
    const int idx = (blk - 12288) * 256 + threadIdx.x;
    const int o = idx >> 11;
    const int rest = idx & 2047;
    const int i = rest >> 5;
    const int kk = rest & 31;
    wcb[(o << 11) + (kk << 6) + i] = f2bf(cw[idx]);
  } else {
    for (int i = threadIdx.x; i < 8192; i += 256) {
      const int bh = i >> 6, d = i & 63;
      kcb[bh * 4096 + 63 * 64 + d] = 0;   // K-block row 63 (pad)
      vcb[bh * 4096 + d * 64 + 63] = 0;   // V col 63 (pad)
    }
  }
}

// ---------- MFMA GEMM: out[M,N] = A[M,K](bf16) * B[N,K](bf16)^T ----------
// 128x128 tile, BK=32, 256 threads; global_load_lds width=16 (m97 pattern).
template <int OUT_BF16>
__global__ __launch_bounds__(256) void gemm_bt(const u16* __restrict__ A,
                                               const u16* __restrict__ Bm,
                                               void* __restrict__ out,
                                               int M, int N, int K) {
  __shared__ u16 As[128 * 32];
  __shared__ u16 Bs[128 * 32];
  const int tid = threadIdx.x;
  const int lane = tid & 63;
  const int w = tid >> 6;
  const int row0 = blockIdx.x * 128;
  const int col0 = blockIdx.y * 128;
  const int wm = (w >> 1) * 64, wn = (w & 1) * 64;
  const int lr = lane & 15, lq = lane >> 4;
  const int srow = lane >> 2;
  const int scol = (lane & 3) * 8;

  f32x4 acc[4][4] = {};

  for (int k0 = 0; k0 < K; k0 += 32) {
    __syncthreads();
#pragma unroll
    for (int p = 0; p < 2; ++p) {
      const int base_r = p * 64 + w * 16;
      gload_lds16(&A[(size_t)(row0 + base_r + srow) * K + k0 + scol], &As[base_r * 32]);
      gload_lds16(&Bm[(size_t)(col0 + base_r + srow) * K + k0 + scol], &Bs[base_r * 32]);
    }
    __syncthreads();
    bf16x8 af[4], bfr[4];
#pragma unroll
    for (int i = 0; i < 4; ++i) {
      af[i] = *(const bf16x8*)&As[(wm + i * 16 + lr) * 32 + lq * 8];
      bfr[i] = *(const bf16x8*)&Bs[(wn + i * 16 + lr) * 32 + lq * 8];
    }
#pragma unroll
    for (int i = 0; i < 4; ++i)
#pragma unroll
      for (int j = 0; j < 4; ++j)
        acc[i][j] = __builtin_amdgcn_mfma_f32_16x16x32_bf16(af[i], bfr[j], acc[i][j], 0, 0, 0);
  }
#pragma unroll
  for (int i = 0; i < 4; ++i)
#pragma unroll
    for (int j = 0; j < 4; ++j)
#pragma unroll
      for (int rr = 0; rr < 4; ++rr) {
        const int gr = row0 + wm + i * 16 + lq * 4 + rr;
        const int gc = col0 + wn + j * 16 + lr;
        const float v = acc[i][j][rr];
        if (OUT_BF16)
          ((u16*)out)[(size_t)gr * N + gc] = f2bf(v);
        else
          ((float*)out)[(size_t)gr * N + gc] = v;
      }
}

// ---------- compression: conv(K=32,stride16) as GEMM + LN(64) + GELU ----------
// grid (63, 2): y=0 -> kcb[bh][nb][d], y=1 -> vcb[bh][d][nb] (both bf16)
__global__ __launch_bounds__(256) void compress_kernel(const u16* __restrict__ qkv,
                                                       const u16* __restrict__ Wc,
                                                       const float* __restrict__ ln_w,
                                                       u16* __restrict__ kcb,
                                                       u16* __restrict__ vcb) {
  __shared__ u16 As[128 * 32];
  __shared__ u16 Bs[64 * 32];
  __shared__ float Cs[128][65];
  const int srcoff = 1024 + (int)blockIdx.y * 1024;
  const int tid = threadIdx.x;
  const int lane = tid & 63;
  const int w = tid >> 6;
  const int r0 = blockIdx.x * 128;
  const int lr = lane & 15, lq = lane >> 4;

  size_t rowbase[2];
#pragma unroll
  for (int p = 0; p < 2; ++p) {
    const int idx = p * 256 + tid;
    const int r = idx >> 2, c = (idx & 3) * 8;
    const int gr = r0 + r;
    const int bh = gr / 63;
    const int nb = gr - bh * 63;
    const int b = bh >> 4, h = bh & 15;
    rowbase[p] = (size_t)(b * 1024 + nb * 16) * 3072 + srcoff + h * 64 + c;
  }
  const int brow = tid >> 2, bcol = (tid & 3) * 8;

  f32x4 acc[2][4] = {};
  for (int k0 = 0; k0 < 2048; k0 += 32) {
    const int kk = k0 >> 6;
    const int i0 = k0 & 63;
    __syncthreads();
#pragma unroll
    for (int p = 0; p < 2; ++p) {
      const int idx = p * 256 + tid;
      const int r = idx >> 2, c = (idx & 3) * 8;
      *(u32x4*)&As[r * 32 + c] = *(const u32x4*)&qkv[rowbase[p] + (size_t)kk * 3072 + i0];
    }
    *(u32x4*)&Bs[brow * 32 + bcol] = *(const u32x4*)&Wc[(size_t)brow * 2048 + k0 + bcol];
    __syncthreads();
    bf16x8 af[2], bfr[4];
#pragma unroll
    for (int i = 0; i < 2; ++i) af[i] = *(const bf16x8*)&As[(w * 32 + i * 16 + lr) * 32 + lq * 8];
#pragma unroll
    for (int j = 0; j < 4; ++j) bfr[j] = *(const bf16x8*)&Bs[(j * 16 + lr) * 32 + lq * 8];
#pragma unroll
    for (int i = 0; i < 2; ++i)
#pragma unroll
      for (int j = 0; j < 4; ++j)
        acc[i][j] = __builtin_amdgcn_mfma_f32_16x16x32_bf16(af[i], bfr[j], acc[i][j], 0, 0, 0);
  }
  __syncthreads();
#pragma unroll
  for (int i = 0; i < 2; ++i)
#pragma unroll
    for (int j = 0; j < 4; ++j)
#pragma unroll
      for (int rr = 0; rr < 4; ++rr)
        Cs[w * 32 + i * 16 + lq * 4 + rr][j * 16 + lr] = acc[i][j][rr];
  __syncthreads();
  if (tid < 128) {
    const int r = tid;
    const int gr = r0 + r;
    const int bh2 = gr / 63;
    const int nb2 = gr - bh2 * 63;
    float s = 0.f, s2 = 0.f;
#pragma unroll 8
    for (int d = 0; d < 64; ++d) {
      const float xv = Cs[r][d];
      s += xv;
      s2 += xv * xv;
    }
    const float m = s * (1.f / 64.f);
    const float inv = rsqrtf(s2 * (1.f / 64.f) - m * m + 1e-5f);
    if (blockIdx.y == 0) {
      const size_t gb = (size_t)bh2 * 4096 + nb2 * 64;
#pragma unroll 8
      for (int d = 0; d < 64; ++d) {
        const float z = (Cs[r][d] - m) * inv * ln_w[d];
        kcb[gb + d] = f2bf(0.5f * z * (1.f + erff(z * 0.70710678118f)));
      }
    } else {
      const size_t gb = (size_t)bh2 * 4096 + nb2;
#pragma unroll 8
      for (int d = 0; d < 64; ++d) {
        const float z = (Cs[r][d] - m) * inv * ln_w[d];
        vcb[gb + d * 64] = f2bf(0.5f * z * (1.f + erff(z * 0.70710678118f)));
      }
    }
  }
}

// ---------- fused attention: local banded (window 129) + compressed-KV ----------
// grid (B*H, T/64); block 256 = 4 waves; wave w owns query rows w*16..w*16+15.
// Local phase computes only band tiles j in [w, w+8] (9 of 12).
__global__ __launch_bounds__(256) void attn_fused(const u16* __restrict__ qkv,
                                                  const u16* __restrict__ kcb,
                                                  const u16* __restrict__ vcb,
                                                  u16* __restrict__ loc,
                                                  u16* __restrict__ outc) {
  __shared__ __align__(16) char smem[53248];
  u16* Ks = (u16*)smem;            // [192][72] bf16, local phase 1
  u16* Vt = (u16*)smem;            // [64][200] bf16, local phase 2 (overlays Ks)
  u16* Ps = (u16*)(smem + 27648);  // [64][200] bf16
  const int bh = blockIdx.x;
  const int b = bh >> 4, h = bh & 15;
  const int i0 = blockIdx.y * 64;
  const int jbase = i0 - 128;
  const int tid = threadIdx.x;
  const int lane = tid & 63, w = tid >> 6;
  const int lr = lane & 15, lq = lane >> 4;

  // stage K into LDS, V into regs; Q fragments from global
  u32x4 vreg[6];
#pragma unroll
  for (int c = 0; c < 6; ++c) {
    const int lin = c * 256 + tid;
    const int s = lin >> 3, d0 = (lin & 7) * 8;
    const int j = jbase + s;
    u32x4 kval = {0, 0, 0, 0}, vval = {0, 0, 0, 0};
    if (j >= 0) {
      const size_t ro = (size_t)(b * 1024 + j) * 3072 + h * 64 + d0;
      kval = *(const u32x4*)&qkv[ro + 1024];
      vval = *(const u32x4*)&qkv[ro + 2048];
    }
    vreg[c] = vval;
    *(u32x4*)&Ks[s * 72 + d0] = kval;
  }
  bf16x8 qf[2];
  {
    const size_t qrow = (size_t)(b * 1024 + i0 + w * 16 + lr) * 3072 + h * 64;
#pragma unroll
    for (int ks = 0; ks < 2; ++ks) qf[ks] = *(const bf16x8*)&qkv[qrow + ks * 32 + lq * 8];
  }
  __syncthreads();

  // S = Q*K^T over the 9 band tiles jt = w..w+8
  f32x4 sa[9];
#pragma unroll
  for (int j9 = 0; j9 < 9; ++j9) sa[j9] = (f32x4){0.f, 0.f, 0.f, 0.f};
#pragma unroll
  for (int ks = 0; ks < 2; ++ks)
#pragma unroll
    for (int j9 = 0; j9 < 9; ++j9) {
      const int jt = w + j9;
      const bf16x8 kf = *(const bf16x8*)&Ks[(jt * 16 + lr) * 72 + ks * 32 + lq * 8];
      sa[j9] = __builtin_amdgcn_mfma_f32_16x16x32_bf16(qf[ks], kf, sa[j9], 0, 0, 0);
    }

  const float NINF = -__builtin_inff();
  float mx[4] = {NINF, NINF, NINF, NINF};
#pragma unroll
  for (int j9 = 0; j9 < 9; ++j9) {
    const int s = (w + j9) * 16 + lr;
#pragma unroll
    for (int rr = 0; rr < 4; ++rr) {
      const int qi = w * 16 + lq * 4 + rr;
      const bool valid = (jbase + s >= 0) && (s >= qi) && (s <= qi + 128);
      const float v = valid ? sa[j9][rr] * 0.125f : NINF;
      sa[j9][rr] = v;
      mx[rr] = fmaxf(mx[rr], v);
    }
  }
#pragma unroll
  for (int rr = 0; rr < 4; ++rr)
#pragma unroll
    for (int o = 1; o < 16; o <<= 1) mx[rr] = fmaxf(mx[rr], __shfl_xor(mx[rr], o, 64));
  float sum[4] = {0.f, 0.f, 0.f, 0.f};
#pragma unroll
  for (int j9 = 0; j9 < 9; ++j9)
#pragma unroll
    for (int rr = 0; rr < 4; ++rr) {
      const float p = __expf(sa[j9][rr] - mx[rr]);
      sa[j9][rr] = p;
      sum[rr] += p;
    }
#pragma unroll
  for (int rr = 0; rr < 4; ++rr) {
#pragma unroll
    for (int o = 1; o < 16; o <<= 1) sum[rr] += __shfl_xor(sum[rr], o, 64);
    sum[rr] = 1.0f / sum[rr];
  }
  __syncthreads();  // Ks reads done before Vt overlays

  // write P (9 tiles + 1 zero tile to cover the 160-wide PV window) and Vt
#pragma unroll
  for (int j9 = 0; j9 < 9; ++j9) {
    const int jt = w + j9;
#pragma unroll
    for (int rr = 0; rr < 4; ++rr)
      Ps[(w * 16 + lq * 4 + rr) * 200 + jt * 16 + lr] = f2bf(sa[j9][rr] * sum[rr]);
  }
  {
    const int jz = (w == 0) ? 9 : (w == 1) ? 0 : (w == 2) ? 11 : 2;
#pragma unroll
    for (int rr = 0; rr < 4; ++rr) Ps[(w * 16 + lq * 4 + rr) * 200 + jz * 16 + lr] = 0;
  }
#pragma unroll
  for (int c = 0; c < 6; ++c) {
    const int lin = c * 256 + tid;
    const int s = lin >> 3, d0 = (lin & 7) * 8;
    const u32x4 val = vreg[c];
#pragma unroll
    for (int q = 0; q < 4; ++q) {
      Vt[(d0 + 2 * q) * 200 + s] = (u16)(val[q] & 0xffffu);
      Vt[(d0 + 2 * q + 1) * 200 + s] = (u16)(val[q] >> 16);
    }
  }
  __syncthreads();

  // O = P*V over the wave's 160-wide window (5 K-steps)
  const int W = (w >> 1) * 32;  // halfword offset of the window
  f32x4 oa[4];
#pragma unroll
  for (int jt = 0; jt < 4; ++jt) oa[jt] = (f32x4){0.f, 0.f, 0.f, 0.f};
#pragma unroll
  for (int ks = 0; ks < 5; ++ks) {
    const bf16x8 pf = *(const bf16x8*)&Ps[(w * 16 + lr) * 200 + W + ks * 32 + lq * 8];
#pragma unroll
    for (int jt = 0; jt < 4; ++jt) {
      const bf16x8 vf = *(const bf16x8*)&Vt[(jt * 16 + lr) * 200 + W + ks * 32 + lq * 8];
      oa[jt] = __builtin_amdgcn_mfma_f32_16x16x32_bf16(pf, vf, oa[jt], 0, 0, 0);
    }
  }
#pragma unroll
  for (int jt = 0; jt < 4; ++jt)
#pragma unroll
    for (int rr = 0; rr < 4; ++rr)
      loc[(size_t)(b * 1024 + i0 + w * 16 + lq * 4 + rr) * 1024 + h * 64 + jt * 16 + lr] =
          f2bf(oa[jt][rr]);

  // ===== compressed-KV phase (reuses qf and smem) =====
  __syncthreads();
  u16* Kc = (u16*)smem;                  // [64][72]
  u16* Vc = (u16*)(smem + 9216);         // [64][72]
  u16* Pc = (u16*)(smem + 18432);        // [64][72]
  const size_t cb = (size_t)bh * 4096;
  for (int c2 = tid; c2 < 512; c2 += 256) {
    const int nb = c2 >> 3, d0 = (c2 & 7) * 8;
    *(u32x4*)&Kc[nb * 72 + d0] = *(const u32x4*)&kcb[cb + nb * 64 + d0];
  }
  for (int c2 = tid; c2 < 512; c2 += 256) {
    const int d = c2 >> 3, n0 = (c2 & 7) * 8;
    *(u32x4*)&Vc[d * 72 + n0] = *(const u32x4*)&vcb[cb + d * 64 + n0];
  }
  __syncthreads();

  f32x4 ca[4];
#pragma unroll
  for (int j = 0; j < 4; ++j) ca[j] = (f32x4){0.f, 0.f, 0.f, 0.f};
#pragma unroll
  for (int ks = 0; ks < 2; ++ks)
#pragma unroll
    for (int j = 0; j < 4; ++j) {
      const bf16x8 kf = *(const bf16x8*)&Kc[(j * 16 + lr) * 72 + ks * 32 + lq * 8];
      ca[j] = __builtin_amdgcn_mfma_f32_16x16x32_bf16(qf[ks], kf, ca[j], 0, 0, 0);
    }
  float mc[4] = {NINF, NINF, NINF, NINF};
#pragma unroll
  for (int j = 0; j < 4; ++j) {
    const int s = j * 16 + lr;
#pragma unroll
    for (int rr = 0; rr < 4; ++rr) {
      const int i = i0 + w * 16 + lq * 4 + rr;
      const bool valid = (s <= i) && (s < 63);
      const float v = valid ? ca[j][rr] * 0.125f : NINF;
      ca[j][rr] = v;
      mc[rr] = fmaxf(mc[rr], v);
    }
  }
#pragma unroll
  for (int rr = 0; rr < 4; ++rr)
#pragma unroll
    for (int o = 1; o < 16; o <<= 1) mc[rr] = fmaxf(mc[rr], __shfl_xor(mc[rr], o, 64));
  float sc[4] = {0.f, 0.f, 0.f, 0.f};
#pragma unroll
  for (int j = 0; j < 4; ++j)
#pragma unroll
    for (int rr = 0; rr < 4; ++rr) {
      const float p = __expf(ca[j][rr] - mc[rr]);
      ca[j][rr] = p;
      sc[rr] += p;
    }
#pragma unroll
  for (int rr = 0; rr < 4; ++rr) {
#pragma unroll
    for (int o = 1; o < 16; o <<= 1) sc[rr] += __shfl_xor(sc[rr], o, 64);
    sc[rr] = 1.0f / sc[rr];
  }
#pragma unroll
  for (int j = 0; j < 4; ++j)
#pragma unroll
    for (int rr = 0; rr < 4; ++rr)
      Pc[(w * 16 + lq * 4 + rr) * 72 + j * 16 + lr] = f2bf(ca[j][rr] * sc[rr]);
  __syncthreads();

  f32x4 co[4];
#pragma unroll
  for (int jt = 0; jt < 4; ++jt) co[jt] = (f32x4){0.f, 0.f, 0.f, 0.f};
#pragma unroll
  for (int ks = 0; ks < 2; ++ks) {
    const bf16x8 pf = *(const bf16x8*)&Pc[(w * 16 + lr) * 72 + ks * 32 + lq * 8];
#pragma unroll
    for (int jt = 0; jt < 4; ++jt) {
      const bf16x8 vf = *(const bf16x8*)&Vc[(jt * 16 + lr) * 72 + ks * 32 + lq * 8];
      co[jt] = __builtin_amdgcn_mfma_f32_16x16x32_bf16(pf, vf, co[jt], 0, 0, 0);
    }
  }
#pragma unroll
  for (int jt = 0; jt < 4; ++jt)
#pragma unroll
    for (int rr = 0; rr < 4; ++rr)
      outc[(size_t)(b * 1024 + i0 + w * 16 + lq * 4 + rr) * 1024 + h * 64 + jt * 16 + lr] =
          f2bf(co[jt][rr]);
}

// ---------- LN of the 8 last-token local rows + pack feats[8][2048] ----------
__global__ __launch_bounds__(256) void ln_feats(const u16* __restrict__ locb,
                                                const u16* __restrict__ compb,
                                                const float* __restrict__ lnw,
                                                float* __restrict__ feats) {
  const int b = blockIdx.x, tid = threadIdx.x;
  const size_t base = ((size_t)b * 1024 + 1023) * 1024 + tid * 4;
  const f32x4 v = unpack_bf4(*(const u32x2*)&locb[base]);
  float s = v[0] + v[1] + v[2] + v[3];
  float s2 = v[0] * v[0] + v[1] * v[1] + v[2] * v[2] + v[3] * v[3];
  s = wredsum(s);
  s2 = wredsum(s2);
  __shared__ float rs[4], rs2[4];
  const int w = tid >> 6, lane = tid & 63;
  if (!lane) { rs[w] = s; rs2[w] = s2; }
  __syncthreads();
  s = rs[0] + rs[1] + rs[2] + rs[3];
  s2 = rs2[0] + rs2[1] + rs2[2] + rs2[3];
  const float m = s * (1.f / 1024.f);
  const float inv = rsqrtf(s2 * (1.f / 1024.f) - m * m + 1e-5f);
  const f32x4 wv = *(const f32x4*)&lnw[tid * 4];
  f32x4 o;
#pragma unroll
  for (int k = 0; k < 4; ++k) o[k] = (v[k] - m) * inv * wv[k];
  *(f32x4*)&feats[b * 2048 + tid * 4] = o;
  *(f32x4*)&feats[b * 2048 + 1024 + tid * 4] = unpack_bf4(*(const u32x2*)&compb[base]);
}

// ---------- gating GEMV: hraw[b,o] = feats[b,:] . w1[o,:] ----------
__global__ __launch_bounds__(256) void gate_gemv(const float* __restrict__ feats,
                                                 const float* __restrict__ w1,
                                                 float* __restrict__ hraw) {
  const int o = blockIdx.x * 4 + (threadIdx.x >> 6);
  const int lane = threadIdx.x & 63;
  const float* wr = &w1[(size_t)o * 2048];
  float acc[8] = {};
#pragma unroll
  for (int it = 0; it < 8; ++it) {
    const int c = (it * 64 + lane) * 4;
    const f32x4 wv = *(const f32x4*)&wr[c];
#pragma unroll
    for (int b = 0; b < 8; ++b) {
      const f32x4 fv = *(const f32x4*)&feats[b * 2048 + c];
      acc[b] += fv[0] * wv[0] + fv[1] * wv[1] + fv[2] * wv[2] + fv[3] * wv[3];
    }
  }
#pragma unroll
  for (int b = 0; b < 8; ++b) acc[b] = wredsum(acc[b]);
  if (lane == 0) {
#pragma unroll
    for (int b = 0; b < 8; ++b) hraw[b * 1024 + o] = acc[b];
  }
}

// ---------- gating finalize: LN + ReLU + 2-way GEMV + softmax ----------
__global__ __launch_bounds__(256) void gate_fin(const float* __restrict__ hraw,
                                                const float* __restrict__ lnw,
                                                const float* __restrict__ w2,
                                                float* __restrict__ gates) {
  const int b = blockIdx.x, tid = threadIdx.x;
  const f32x4 v = *(const f32x4*)&hraw[(size_t)b * 1024 + tid * 4];
  float s = v[0] + v[1] + v[2] + v[3];
  float s2 = v[0] * v[0] + v[1] * v[1] + v[2] * v[2] + v[3] * v[3];
  s = wredsum(s);
  s2 = wredsum(s2);
  __shared__ float rs[4], rs2[4];
  const int w = tid >> 6, lane = tid & 63;
  if (!lane) { rs[w] = s; rs2[w] = s2; }
  __syncthreads();
  s = rs[0] + rs[1] + rs[2] + rs[3];
  s2 = rs2[0] + rs2[1] + rs2[2] + rs2[3];
  const float m = s * (1.f / 1024.f);
  const float inv = rsqrtf(s2 * (1.f / 1024.f) - m * m + 1e-5f);
  float p0 = 0.f, p1 = 0.f;
#pragma unroll
  for (int k = 0; k < 4; ++k) {
    float hh = (v[k] - m) * inv * lnw[tid * 4 + k];
    hh = fmaxf(hh, 0.f);
    p0 += hh * w2[tid * 4 + k];
    p1 += hh * w2[1024 + tid * 4 + k];
  }
  p0 = wredsum(p0);
  p1 = wredsum(p1);
  __syncthreads();
  if (!lane) { rs[w] = p0; rs2[w] = p1; }
  __syncthreads();
  if (tid == 0) {
    const float l0 = rs[0] + rs[1] + rs[2] + rs[3];
    const float l1 = rs2[0] + rs2[1] + rs2[2] + rs2[3];
    const float mm = fmaxf(l0, l1);
    const float e0 = __expf(l0 - mm), e1 = __expf(l1 - mm);
    const float iv = 1.f / (e0 + e1);
    gates[b * 2] = e0 * iv;
    gates[b * 2 + 1] = e1 * iv;
  }
}

// ---------- fused: per-row LN of local_out + gate-combine + bf16 cast ----------
__global__ __launch_bounds__(256) void combine_ln_cast(const u16* __restrict__ locb,
                                                       const u16* __restrict__ compb,
                                                       const float* __restrict__ lnw,
                                                       const float* __restrict__ gates,
                                                       u16* __restrict__ outb) {
  const int row = blockIdx.x, tid = threadIdx.x;
  const size_t base = (size_t)row * 1024 + tid * 4;
  const f32x4 v = unpack_bf4(*(const u32x2*)&locb[base]);
  float s = v[0] + v[1] + v[2] + v[3];
  float s2 = v[0] * v[0] + v[1] * v[1] + v[2] * v[2] + v[3] * v[3];
  s = wredsum(s);
  s2 = wredsum(s2);
  __shared__ float rs[4], rs2[4];
  const int w = tid >> 6, lane = tid & 63;
  if (!lane) { rs[w] = s; rs2[w] = s2; }
  __syncthreads();
  s = rs[0] + rs[1] + rs[2] + rs[3];
  s2 = rs2[0] + rs2[1] + rs2[2] + rs2[3];
  const float m = s * (1.f / 1024.f);
  const float inv = rsqrtf(s2 * (1.f / 1024.f) - m * m + 1e-5f);
  const int b = row >> 10;
  const float g0 = gates[2 * b], g1 = gates[2 * b + 1];
  const f32x4 wv = *(const f32x4*)&lnw[tid * 4];
  const f32x4 c = unpack_bf4(*(const u32x2*)&compb[base]);
  float ov[4];
#pragma unroll
  for (int k = 0; k < 4; ++k) ov[k] = g0 * ((v[k] - m) * inv * wv[k]) + g1 * c[k];
  u32x2 r;
  r[0] = (u32)f2bf(ov[0]) | ((u32)f2bf(ov[1]) << 16);
  r[1] = (u32)f2bf(ov[2]) | ((u32)f2bf(ov[3]) << 16);
  *(u32x2*)&outb[base] = r;
}

// ---------- launcher ----------
extern "C" void kernel_launch(void* const* d_in, const int* in_sizes, int n_in,
                              void* d_out, int out_size, void* d_ws, size_t ws_size,
                              hipStream_t stream) {
  const float* x = (const float*)d_in[0];
  const float* c_attn_w = (const float*)d_in[1];
  const float* conv_w = (const float*)d_in[2];
  const float* ln_comp_w = (const float*)d_in[3];
  const float* ln_local_w = (const float*)d_in[4];
  const float* gate_w1 = (const float*)d_in[5];
  const float* gate_ln_w = (const float*)d_in[6];
  const float* gate_w2 = (const float*)d_in[7];
  const float* c_proj_w = (const float*)d_in[8];
  float* y = (float*)d_out;

  char* ws = (char*)d_ws;
  size_t off = 0;
  auto alloc = [&](size_t bytes) -> void* {
    void* p = ws + off;
    off += (bytes + 255) & ~(size_t)255;
    return p;
  };
  u16* qkvb = (u16*)alloc((size_t)8192 * 3072 * 2);
  u16* xb = (u16*)alloc((size_t)8192 * 1024 * 2);
  u16* wab = (u16*)alloc((size_t)3072 * 1024 * 2);
  u16* wpb = (u16*)alloc((size_t)1024 * 1024 * 2);
  u16* wcb = (u16*)alloc((size_t)64 * 2048 * 2);
  u16* kcb = (u16*)alloc((size_t)128 * 4096 * 2);  // [bh][nb(64)][d] bf16
  u16* vcb = (u16*)alloc((size_t)128 * 4096 * 2);  // [bh][d][nb(64)] bf16
  u16* locb = (u16*)alloc((size_t)8192 * 1024 * 2);
  u16* compb = (u16*)alloc((size_t)8192 * 1024 * 2);
  float* feats = (float*)alloc((size_t)8 * 2048 * 4);
  float* hraw = (float*)alloc((size_t)8192 * 4);
  float* gates = (float*)alloc(64);
  u16* combb = (u16*)alloc((size_t)8192 * 1024 * 2);

  fused_cast<<<12801, 256, 0, stream>>>(x, c_attn_w, c_proj_w, conv_w, xb, wab, wpb, wcb, kcb,
                                        vcb);

  gemm_bt<1><<<dim3(64, 24), 256, 0, stream>>>(xb, wab, qkvb, 8192, 3072, 1024);

  compress_kernel<<<dim3(63, 2), 256, 0, stream>>>(qkvb, wcb, ln_comp_w, kcb, vcb);

  attn_fused<<<dim3(128, 16), 256, 0, stream>>>(qkvb, kcb, vcb, locb, compb);

  ln_feats<<<8, 256, 0, stream>>>(locb, compb, ln_local_w, feats);
  gate_gemv<<<256, 256, 0, stream>>>(feats, gate_w1, hraw);
  gate_fin<<<8, 256, 0, stream>>>(hraw, gate_ln_w, gate_w2, gates);

  combine_ln_cast<<<8192, 256, 0, stream>>>(locb, compb, ln_local_w, gates, combb);

  gemm_bt<0><<<dim3(64, 8), 256, 0, stream>>>(combb, wpb, y, 8192, 1024, 1024);
}

// Round 5
// 300.115 us; speedup vs baseline: 3.1883x; 1.0462x over previous
//
#include <hip/hip_runtime.h>
#include <cstdint>
#include <cmath>
#include <cstddef>

typedef unsigned int u32;
typedef unsigned short u16;
typedef __bf16 bf16x8 __attribute__((ext_vector_type(8)));
typedef float f32x4 __attribute__((ext_vector_type(4)));
typedef u32 u32x4 __attribute__((ext_vector_type(4)));
typedef u32 u32x2 __attribute__((ext_vector_type(2)));

#define DEV static __device__ __forceinline__

// ---------- helpers ----------
DEV float bflo(u32 u) { return __uint_as_float(u << 16); }
DEV float bfhi(u32 u) { return __uint_as_float(u & 0xffff0000u); }
DEV u16 f2bf(float f) {               // RNE fp32 -> bf16
  u32 u = __float_as_uint(f);
  u += 0x7fffu + ((u >> 16) & 1u);
  return (u16)(u >> 16);
}
DEV f32x4 unpack_bf4(u32x2 r) {
  return (f32x4){bflo(r[0]), bfhi(r[0]), bflo(r[1]), bfhi(r[1])};
}
DEV float wredsum(float v) {
#pragma unroll
  for (int o = 32; o; o >>= 1) v += __shfl_xor(v, o, 64);
  return v;
}

// async global->LDS, 16B per lane. LDS dest is wave-uniform base + lane*16.
DEV void gload_lds16(const u16* g, u16* lds_base) {
  __builtin_amdgcn_global_load_lds((const __attribute__((address_space(1))) void*)g,
                                   (__attribute__((address_space(3))) void*)lds_base,
                                   16, 0, 0);
}

// ---------- fused casts + workspace pad zeroing ----------
// blocks 0..8191: x; 8192..11263: c_attn_w; 11264..12287: c_proj_w;
// 12288..12799: conv_w repack; 12800: zero kcb row63 / vcb col63 pads.
__global__ __launch_bounds__(256) void fused_cast(const float* __restrict__ x,
                                                  const float* __restrict__ aw,
                                                  const float* __restrict__ pw,
                                                  const float* __restrict__ cw,
                                                  u16* __restrict__ xb,
                                                  u16* __restrict__ wab,
                                                  u16* __restrict__ wpb,
                                                  u16* __restrict__ wcb,
                                                  u16* __restrict__ kcb,
                                                  u16* __restrict__ vcb) {
  const int blk = blockIdx.x;
  if (blk < 12288) {
    const float* src;
    u16* dst;
    int base;
    if (blk < 8192) { src = x; dst = xb; base = blk; }
    else if (blk < 11264) { src = aw; dst = wab; base = blk - 8192; }
    else { src = pw; dst = wpb; base = blk - 11264; }
    const size_t idx = ((size_t)base * 256 + threadIdx.x) * 4;
    const f32x4 v = *(const f32x4*)&src[idx];
    u32x2 r;
    r[0] = (u32)f2bf(v[0]) | ((u32)f2bf(v[1]) << 16);
    r[1] = (u32)f2bf(v[2]) | ((u32)f2bf(v[3]) << 16);
    *(u32x2*)&dst[idx] = r;
  } else if (blk < 12800) {
    // conv_w [64][64][32] (o,i,kk) fp32 -> Wc[o][kk*64+i] bf16
    const int idx = (blk - 12288) * 256 + threadIdx.x;
    const int o = idx >> 11;
    const int rest = idx & 2047;
    const int i = rest >> 5;
    const int kk = rest & 31;
    wcb[(o << 11) + (kk << 6) + i] = f2bf(cw[idx]);
  } else {
    for (int i = threadIdx.x; i < 8192; i += 256) {
      const int bh = i >> 6, d = i & 63;
      kcb[bh * 4096 + 63 * 64 + d] = 0;   // K-block row 63 (pad)
      vcb[bh * 4096 + d * 64 + 63] = 0;   // V col 63 (pad)
    }
  }
}

// ---------- MFMA GEMM: out[M,N] = A[M,K](bf16) * B[N,K](bf16)^T ----------
// 128x128 tile, BK=32, 256 threads; global_load_lds width=16 (m97 pattern).
// __launch_bounds__(256,4): force <=128 VGPR for 4 waves/SIMD (we sit at ~132).
template <int OUT_BF16>
__global__ __launch_bounds__(256, 4) void gemm_bt(const u16* __restrict__ A,
                                                  const u16* __restrict__ Bm,
                                                  void* __restrict__ out,
                                                  int M, int N, int K) {
  __shared__ u16 As[128 * 32];
  __shared__ u16 Bs[128 * 32];
  const int tid = threadIdx.x;
  const int lane = tid & 63;
  const int w = tid >> 6;
  const int row0 = blockIdx.x * 128;
  const int col0 = blockIdx.y * 128;
  const int wm = (w >> 1) * 64, wn = (w & 1) * 64;
  const int lr = lane & 15, lq = lane >> 4;
  const int srow = lane >> 2;
  const int scol = (lane & 3) * 8;

  f32x4 acc[4][4] = {};

  for (int k0 = 0; k0 < K; k0 += 32) {
    __syncthreads();
#pragma unroll
    for (int p = 0; p < 2; ++p) {
      const int base_r = p * 64 + w * 16;
      gload_lds16(&A[(size_t)(row0 + base_r + srow) * K + k0 + scol], &As[base_r * 32]);
      gload_lds16(&Bm[(size_t)(col0 + base_r + srow) * K + k0 + scol], &Bs[base_r * 32]);
    }
    __syncthreads();
    bf16x8 af[4], bfr[4];
#pragma unroll
    for (int i = 0; i < 4; ++i) {
      af[i] = *(const bf16x8*)&As[(wm + i * 16 + lr) * 32 + lq * 8];
      bfr[i] = *(const bf16x8*)&Bs[(wn + i * 16 + lr) * 32 + lq * 8];
    }
#pragma unroll
    for (int i = 0; i < 4; ++i)
#pragma unroll
      for (int j = 0; j < 4; ++j)
        acc[i][j] = __builtin_amdgcn_mfma_f32_16x16x32_bf16(af[i], bfr[j], acc[i][j], 0, 0, 0);
  }
#pragma unroll
  for (int i = 0; i < 4; ++i)
#pragma unroll
    for (int j = 0; j < 4; ++j)
#pragma unroll
      for (int rr = 0; rr < 4; ++rr) {
        const int gr = row0 + wm + i * 16 + lq * 4 + rr;
        const int gc = col0 + wn + j * 16 + lr;
        const float v = acc[i][j][rr];
        if (OUT_BF16)
          ((u16*)out)[(size_t)gr * N + gc] = f2bf(v);
        else
          ((float*)out)[(size_t)gr * N + gc] = v;
      }
}

// ---------- compression: conv(K=32,stride16) as GEMM + LN(64) + GELU ----------
// 64-row tiles, grid (126, 2): y=0 -> kcb[bh][nb][d], y=1 -> vcb[bh][d][nb].
// True double-buffered async staging: barrier drains buf k, THEN issue stage
// of k+1 (stays in flight across the whole compute span) -- this block runs at
// ~1 block/CU so there is no TLP to hide latency implicitly.
__global__ __launch_bounds__(256) void compress_kernel(const u16* __restrict__ qkv,
                                                       const u16* __restrict__ Wc,
                                                       const float* __restrict__ ln_w,
                                                       u16* __restrict__ kcb,
                                                       u16* __restrict__ vcb) {
  __shared__ u16 As[2][64 * 32];
  __shared__ u16 Bs[2][64 * 32];
  __shared__ float Cs[64][65];
  const int tid = threadIdx.x;
  const int lane = tid & 63, w = tid >> 6;
  const int lr = lane & 15, lq = lane >> 4;
  const int r0 = blockIdx.x * 64;
  const int srcoff = 1024 + (int)blockIdx.y * 1024;

  // per-thread global source for A: row tid>>2 of tile, col (tid&3)*8
  const int arow = tid >> 2, acol = (tid & 3) * 8;
  const int gr = r0 + arow;
  const int bh = gr / 63;
  const int nb = gr - bh * 63;
  const int b = bh >> 4, h = bh & 15;
  const size_t abase = (size_t)(b * 1024 + nb * 16) * 3072 + srcoff + h * 64 + acol;
  const size_t bbase = (size_t)arow * 2048 + acol;

  f32x4 acc[4] = {};
  // prologue stage k0=0 into buf 0
  {
    gload_lds16(&qkv[abase], &As[0][w * 512]);
    gload_lds16(&Wc[bbase], &Bs[0][w * 512]);
  }
  for (int it = 0; it < 64; ++it) {
    const int cur = it & 1;
    __syncthreads();  // drains stage for buf cur; also joins waves
    if (it < 63) {
      const int k0 = (it + 1) * 32;
      const int kk = k0 >> 6, i0 = k0 & 63;
      gload_lds16(&qkv[abase + (size_t)kk * 3072 + i0], &As[cur ^ 1][w * 512]);
      gload_lds16(&Wc[bbase + k0], &Bs[cur ^ 1][w * 512]);
    }
    const bf16x8 af = *(const bf16x8*)&As[cur][(w * 16 + lr) * 32 + lq * 8];
#pragma unroll
    for (int j = 0; j < 4; ++j) {
      const bf16x8 bfr = *(const bf16x8*)&Bs[cur][(j * 16 + lr) * 32 + lq * 8];
      acc[j] = __builtin_amdgcn_mfma_f32_16x16x32_bf16(af, bfr, acc[j], 0, 0, 0);
    }
  }
  __syncthreads();
#pragma unroll
  for (int j = 0; j < 4; ++j)
#pragma unroll
    for (int rr = 0; rr < 4; ++rr)
      Cs[w * 16 + lq * 4 + rr][j * 16 + lr] = acc[j][rr];
  __syncthreads();
  if (tid < 64) {
    const int gr2 = r0 + tid;
    const int bh2 = gr2 / 63;
    const int nb2 = gr2 - bh2 * 63;
    float s = 0.f, s2 = 0.f;
#pragma unroll 8
    for (int d = 0; d < 64; ++d) {
      const float xv = Cs[tid][d];
      s += xv;
      s2 += xv * xv;
    }
    const float m = s * (1.f / 64.f);
    const float inv = rsqrtf(s2 * (1.f / 64.f) - m * m + 1e-5f);
    if (blockIdx.y == 0) {
      const size_t gb = (size_t)bh2 * 4096 + nb2 * 64;
#pragma unroll 8
      for (int d = 0; d < 64; ++d) {
        const float z = (Cs[tid][d] - m) * inv * ln_w[d];
        kcb[gb + d] = f2bf(0.5f * z * (1.f + erff(z * 0.70710678118f)));
      }
    } else {
      const size_t gb = (size_t)bh2 * 4096 + nb2;
#pragma unroll 8
      for (int d = 0; d < 64; ++d) {
        const float z = (Cs[tid][d] - m) * inv * ln_w[d];
        vcb[gb + d * 64] = f2bf(0.5f * z * (1.f + erff(z * 0.70710678118f)));
      }
    }
  }
}

// ---------- fused attention: local banded (window 129) + compressed-KV ----------
// grid (B*H, T/64); block 256 = 4 waves; wave w owns query rows w*16..w*16+15.
// Local phase computes only band tiles j in [w, w+8] (9 of 12).
__global__ __launch_bounds__(256) void attn_fused(const u16* __restrict__ qkv,
                                                  const u16* __restrict__ kcb,
                                                  const u16* __restrict__ vcb,
                                                  u16* __restrict__ loc,
                                                  u16* __restrict__ outc) {
  __shared__ __align__(16) char smem[53248];
  u16* Ks = (u16*)smem;            // [192][72] bf16, local phase 1
  u16* Vt = (u16*)smem;            // [64][200] bf16, local phase 2 (overlays Ks)
  u16* Ps = (u16*)(smem + 27648);  // [64][200] bf16
  const int bh = blockIdx.x;
  const int b = bh >> 4, h = bh & 15;
  const int i0 = blockIdx.y * 64;
  const int jbase = i0 - 128;
  const int tid = threadIdx.x;
  const int lane = tid & 63, w = tid >> 6;
  const int lr = lane & 15, lq = lane >> 4;

  // stage K into LDS, V into regs; Q fragments from global
  u32x4 vreg[6];
#pragma unroll
  for (int c = 0; c < 6; ++c) {
    const int lin = c * 256 + tid;
    const int s = lin >> 3, d0 = (lin & 7) * 8;
    const int j = jbase + s;
    u32x4 kval = {0, 0, 0, 0}, vval = {0, 0, 0, 0};
    if (j >= 0) {
      const size_t ro = (size_t)(b * 1024 + j) * 3072 + h * 64 + d0;
      kval = *(const u32x4*)&qkv[ro + 1024];
      vval = *(const u32x4*)&qkv[ro + 2048];
    }
    vreg[c] = vval;
    *(u32x4*)&Ks[s * 72 + d0] = kval;
  }
  bf16x8 qf[2];
  {
    const size_t qrow = (size_t)(b * 1024 + i0 + w * 16 + lr) * 3072 + h * 64;
#pragma unroll
    for (int ks = 0; ks < 2; ++ks) qf[ks] = *(const bf16x8*)&qkv[qrow + ks * 32 + lq * 8];
  }
  __syncthreads();

  // S = Q*K^T over the 9 band tiles jt = w..w+8
  f32x4 sa[9];
#pragma unroll
  for (int j9 = 0; j9 < 9; ++j9) sa[j9] = (f32x4){0.f, 0.f, 0.f, 0.f};
#pragma unroll
  for (int ks = 0; ks < 2; ++ks)
#pragma unroll
    for (int j9 = 0; j9 < 9; ++j9) {
      const int jt = w + j9;
      const bf16x8 kf = *(const bf16x8*)&Ks[(jt * 16 + lr) * 72 + ks * 32 + lq * 8];
      sa[j9] = __builtin_amdgcn_mfma_f32_16x16x32_bf16(qf[ks], kf, sa[j9], 0, 0, 0);
    }

  const float NINF = -__builtin_inff();
  float mx[4] = {NINF, NINF, NINF, NINF};
#pragma unroll
  for (int j9 = 0; j9 < 9; ++j9) {
    const int s = (w + j9) * 16 + lr;
#pragma unroll
    for (int rr = 0; rr < 4; ++rr) {
      const int qi = w * 16 + lq * 4 + rr;
      const bool valid = (jbase + s >= 0) && (s >= qi) && (s <= qi + 128);
      const float v = valid ? sa[j9][rr] * 0.125f : NINF;
      sa[j9][rr] = v;
      mx[rr] = fmaxf(mx[rr], v);
    }
  }
#pragma unroll
  for (int rr = 0; rr < 4; ++rr)
#pragma unroll
    for (int o = 1; o < 16; o <<= 1) mx[rr] = fmaxf(mx[rr], __shfl_xor(mx[rr], o, 64));
  float sum[4] = {0.f, 0.f, 0.f, 0.f};
#pragma unroll
  for (int j9 = 0; j9 < 9; ++j9)
#pragma unroll
    for (int rr = 0; rr < 4; ++rr) {
      const float p = __expf(sa[j9][rr] - mx[rr]);
      sa[j9][rr] = p;
      sum[rr] += p;
    }
#pragma unroll
  for (int rr = 0; rr < 4; ++rr) {
#pragma unroll
    for (int o = 1; o < 16; o <<= 1) sum[rr] += __shfl_xor(sum[rr], o, 64);
    sum[rr] = 1.0f / sum[rr];
  }
  __syncthreads();  // Ks reads done before Vt overlays

  // write P (9 tiles + 1 zero tile to cover the 160-wide PV window) and Vt
#pragma unroll
  for (int j9 = 0; j9 < 9; ++j9) {
    const int jt = w + j9;
#pragma unroll
    for (int rr = 0; rr < 4; ++rr)
      Ps[(w * 16 + lq * 4 + rr) * 200 + jt * 16 + lr] = f2bf(sa[j9][rr] * sum[rr]);
  }
  {
    const int jz = (w == 0) ? 9 : (w == 1) ? 0 : (w == 2) ? 11 : 2;
#pragma unroll
    for (int rr = 0; rr < 4; ++rr) Ps[(w * 16 + lq * 4 + rr) * 200 + jz * 16 + lr] = 0;
  }
#pragma unroll
  for (int c = 0; c < 6; ++c) {
    const int lin = c * 256 + tid;
    const int s = lin >> 3, d0 = (lin & 7) * 8;
    const u32x4 val = vreg[c];
#pragma unroll
    for (int q = 0; q < 4; ++q) {
      Vt[(d0 + 2 * q) * 200 + s] = (u16)(val[q] & 0xffffu);
      Vt[(d0 + 2 * q + 1) * 200 + s] = (u16)(val[q] >> 16);
    }
  }
  __syncthreads();

  // O = P*V over the wave's 160-wide window (5 K-steps)
  const int W = (w >> 1) * 32;  // halfword offset of the window
  f32x4 oa[4];
#pragma unroll
  for (int jt = 0; jt < 4; ++jt) oa[jt] = (f32x4){0.f, 0.f, 0.f, 0.f};
#pragma unroll
  for (int ks = 0; ks < 5; ++ks) {
    const bf16x8 pf = *(const bf16x8*)&Ps[(w * 16 + lr) * 200 + W + ks * 32 + lq * 8];
#pragma unroll
    for (int jt = 0; jt < 4; ++jt) {
      const bf16x8 vf = *(const bf16x8*)&Vt[(jt * 16 + lr) * 200 + W + ks * 32 + lq * 8];
      oa[jt] = __builtin_amdgcn_mfma_f32_16x16x32_bf16(pf, vf, oa[jt], 0, 0, 0);
    }
  }
#pragma unroll
  for (int jt = 0; jt < 4; ++jt)
#pragma unroll
    for (int rr = 0; rr < 4; ++rr)
      loc[(size_t)(b * 1024 + i0 + w * 16 + lq * 4 + rr) * 1024 + h * 64 + jt * 16 + lr] =
          f2bf(oa[jt][rr]);

  // ===== compressed-KV phase (reuses qf and smem) =====
  __syncthreads();
  u16* Kc = (u16*)smem;                  // [64][72]
  u16* Vc = (u16*)(smem + 9216);         // [64][72]
  u16* Pc = (u16*)(smem + 18432);        // [64][72]
  const size_t cb = (size_t)bh * 4096;
  for (int c2 = tid; c2 < 512; c2 += 256) {
    const int nb = c2 >> 3, d0 = (c2 & 7) * 8;
    *(u32x4*)&Kc[nb * 72 + d0] = *(const u32x4*)&kcb[cb + nb * 64 + d0];
  }
  for (int c2 = tid; c2 < 512; c2 += 256) {
    const int d = c2 >> 3, n0 = (c2 & 7) * 8;
    *(u32x4*)&Vc[d * 72 + n0] = *(const u32x4*)&vcb[cb + d * 64 + n0];
  }
  __syncthreads();

  f32x4 ca[4];
#pragma unroll
  for (int j = 0; j < 4; ++j) ca[j] = (f32x4){0.f, 0.f, 0.f, 0.f};
#pragma unroll
  for (int ks = 0; ks < 2; ++ks)
#pragma unroll
    for (int j = 0; j < 4; ++j) {
      const bf16x8 kf = *(const bf16x8*)&Kc[(j * 16 + lr) * 72 + ks * 32 + lq * 8];
      ca[j] = __builtin_amdgcn_mfma_f32_16x16x32_bf16(qf[ks], kf, ca[j], 0, 0, 0);
    }
  float mc[4] = {NINF, NINF, NINF, NINF};
#pragma unroll
  for (int j = 0; j < 4; ++j) {
    const int s = j * 16 + lr;
#pragma unroll
    for (int rr = 0; rr < 4; ++rr) {
      const int i = i0 + w * 16 + lq * 4 + rr;
      const bool valid = (s <= i) && (s < 63);
      const float v = valid ? ca[j][rr] * 0.125f : NINF;
      ca[j][rr] = v;
      mc[rr] = fmaxf(mc[rr], v);
    }
  }
#pragma unroll
  for (int rr = 0; rr < 4; ++rr)
#pragma unroll
    for (int o = 1; o < 16; o <<= 1) mc[rr] = fmaxf(mc[rr], __shfl_xor(mc[rr], o, 64));
  float sc[4] = {0.f, 0.f, 0.f, 0.f};
#pragma unroll
  for (int j = 0; j < 4; ++j)
#pragma unroll
    for (int rr = 0; rr < 4; ++rr) {
      const float p = __expf(ca[j][rr] - mc[rr]);
      ca[j][rr] = p;
      sc[rr] += p;
    }
#pragma unroll
  for (int rr = 0; rr < 4; ++rr) {
#pragma unroll
    for (int o = 1; o < 16; o <<= 1) sc[rr] += __shfl_xor(sc[rr], o, 64);
    sc[rr] = 1.0f / sc[rr];
  }
#pragma unroll
  for (int j = 0; j < 4; ++j)
#pragma unroll
    for (int rr = 0; rr < 4; ++rr)
      Pc[(w * 16 + lq * 4 + rr) * 72 + j * 16 + lr] = f2bf(ca[j][rr] * sc[rr]);
  __syncthreads();

  f32x4 co[4];
#pragma unroll
  for (int jt = 0; jt < 4; ++jt) co[jt] = (f32x4){0.f, 0.f, 0.f, 0.f};
#pragma unroll
  for (int ks = 0; ks < 2; ++ks) {
    const bf16x8 pf = *(const bf16x8*)&Pc[(w * 16 + lr) * 72 + ks * 32 + lq * 8];
#pragma unroll
    for (int jt = 0; jt < 4; ++jt) {
      const bf16x8 vf = *(const bf16x8*)&Vc[(jt * 16 + lr) * 72 + ks * 32 + lq * 8];
      co[jt] = __builtin_amdgcn_mfma_f32_16x16x32_bf16(pf, vf, co[jt], 0, 0, 0);
    }
  }
#pragma unroll
  for (int jt = 0; jt < 4; ++jt)
#pragma unroll
    for (int rr = 0; rr < 4; ++rr)
      outc[(size_t)(b * 1024 + i0 + w * 16 + lq * 4 + rr) * 1024 + h * 64 + jt * 16 + lr] =
          f2bf(co[jt][rr]);
}

// ---------- LN of the 8 last-token local rows + pack feats[8][2048] ----------
__global__ __launch_bounds__(256) void ln_feats(const u16* __restrict__ locb,
                                                const u16* __restrict__ compb,
                                                const float* __restrict__ lnw,
                                                float* __restrict__ feats) {
  const int b = blockIdx.x, tid = threadIdx.x;
  const size_t base = ((size_t)b * 1024 + 1023) * 1024 + tid * 4;
  const f32x4 v = unpack_bf4(*(const u32x2*)&locb[base]);
  float s = v[0] + v[1] + v[2] + v[3];
  float s2 = v[0] * v[0] + v[1] * v[1] + v[2] * v[2] + v[3] * v[3];
  s = wredsum(s);
  s2 = wredsum(s2);
  __shared__ float rs[4], rs2[4];
  const int w = tid >> 6, lane = tid & 63;
  if (!lane) { rs[w] = s; rs2[w] = s2; }
  __syncthreads();
  s = rs[0] + rs[1] + rs[2] + rs[3];
  s2 = rs2[0] + rs2[1] + rs2[2] + rs2[3];
  const float m = s * (1.f / 1024.f);
  const float inv = rsqrtf(s2 * (1.f / 1024.f) - m * m + 1e-5f);
  const f32x4 wv = *(const f32x4*)&lnw[tid * 4];
  f32x4 o;
#pragma unroll
  for (int k = 0; k < 4; ++k) o[k] = (v[k] - m) * inv * wv[k];
  *(f32x4*)&feats[b * 2048 + tid * 4] = o;
  *(f32x4*)&feats[b * 2048 + 1024 + tid * 4] = unpack_bf4(*(const u32x2*)&compb[base]);
}

// ---------- gating GEMV: hraw[b,o] = feats[b,:] . w1[o,:] ----------
__global__ __launch_bounds__(256) void gate_gemv(const float* __restrict__ feats,
                                                 const float* __restrict__ w1,
                                                 float* __restrict__ hraw) {
  const int o = blockIdx.x * 4 + (threadIdx.x >> 6);
  const int lane = threadIdx.x & 63;
  const float* wr = &w1[(size_t)o * 2048];
  float acc[8] = {};
#pragma unroll
  for (int it = 0; it < 8; ++it) {
    const int c = (it * 64 + lane) * 4;
    const f32x4 wv = *(const f32x4*)&wr[c];
#pragma unroll
    for (int b = 0; b < 8; ++b) {
      const f32x4 fv = *(const f32x4*)&feats[b * 2048 + c];
      acc[b] += fv[0] * wv[0] + fv[1] * wv[1] + fv[2] * wv[2] + fv[3] * wv[3];
    }
  }
#pragma unroll
  for (int b = 0; b < 8; ++b) acc[b] = wredsum(acc[b]);
  if (lane == 0) {
#pragma unroll
    for (int b = 0; b < 8; ++b) hraw[b * 1024 + o] = acc[b];
  }
}

// ---------- gating finalize: LN + ReLU + 2-way GEMV + softmax ----------
__global__ __launch_bounds__(256) void gate_fin(const float* __restrict__ hraw,
                                                const float* __restrict__ lnw,
                                                const float* __restrict__ w2,
                                                float* __restrict__ gates) {
  const int b = blockIdx.x, tid = threadIdx.x;
  const f32x4 v = *(const f32x4*)&hraw[(size_t)b * 1024 + tid * 4];
  float s = v[0] + v[1] + v[2] + v[3];
  float s2 = v[0] * v[0] + v[1] * v[1] + v[2] * v[2] + v[3] * v[3];
  s = wredsum(s);
  s2 = wredsum(s2);
  __shared__ float rs[4], rs2[4];
  const int w = tid >> 6, lane = tid & 63;
  if (!lane) { rs[w] = s; rs2[w] = s2; }
  __syncthreads();
  s = rs[0] + rs[1] + rs[2] + rs[3];
  s2 = rs2[0] + rs2[1] + rs2[2] + rs2[3];
  const float m = s * (1.f / 1024.f);
  const float inv = rsqrtf(s2 * (1.f / 1024.f) - m * m + 1e-5f);
  float p0 = 0.f, p1 = 0.f;
#pragma unroll
  for (int k = 0; k < 4; ++k) {
    float hh = (v[k] - m) * inv * lnw[tid * 4 + k];
    hh = fmaxf(hh, 0.f);
    p0 += hh * w2[tid * 4 + k];
    p1 += hh * w2[1024 + tid * 4 + k];
  }
  p0 = wredsum(p0);
  p1 = wredsum(p1);
  __syncthreads();
  if (!lane) { rs[w] = p0; rs2[w] = p1; }
  __syncthreads();
  if (tid == 0) {
    const float l0 = rs[0] + rs[1] + rs[2] + rs[3];
    const float l1 = rs2[0] + rs2[1] + rs2[2] + rs2[3];
    const float mm = fmaxf(l0, l1);
    const float e0 = __expf(l0 - mm), e1 = __expf(l1 - mm);
    const float iv = 1.f / (e0 + e1);
    gates[b * 2] = e0 * iv;
    gates[b * 2 + 1] = e1 * iv;
  }
}

// ---------- fused: per-row LN of local_out + gate-combine + bf16 cast ----------
__global__ __launch_bounds__(256) void combine_ln_cast(const u16* __restrict__ locb,
                                                       const u16* __restrict__ compb,
                                                       const float* __restrict__ lnw,
                                                       const float* __restrict__ gates,
                                                       u16* __restrict__ outb) {
  const int row = blockIdx.x, tid = threadIdx.x;
  const size_t base = (size_t)row * 1024 + tid * 4;
  const f32x4 v = unpack_bf4(*(const u32x2*)&locb[base]);
  float s = v[0] + v[1] + v[2] + v[3];
  float s2 = v[0] * v[0] + v[1] * v[1] + v[2] * v[2] + v[3] * v[3];
  s = wredsum(s);
  s2 = wredsum(s2);
  __shared__ float rs[4], rs2[4];
  const int w = tid >> 6, lane = tid & 63;
  if (!lane) { rs[w] = s; rs2[w] = s2; }
  __syncthreads();
  s = rs[0] + rs[1] + rs[2] + rs[3];
  s2 = rs2[0] + rs2[1] + rs2[2] + rs2[3];
  const float m = s * (1.f / 1024.f);
  const float inv = rsqrtf(s2 * (1.f / 1024.f) - m * m + 1e-5f);
  const int b = row >> 10;
  const float g0 = gates[2 * b], g1 = gates[2 * b + 1];
  const f32x4 wv = *(const f32x4*)&lnw[tid * 4];
  const f32x4 c = unpack_bf4(*(const u32x2*)&compb[base]);
  float ov[4];
#pragma unroll
  for (int k = 0; k < 4; ++k) ov[k] = g0 * ((v[k] - m) * inv * wv[k]) + g1 * c[k];
  u32x2 r;
  r[0] = (u32)f2bf(ov[0]) | ((u32)f2bf(ov[1]) << 16);
  r[1] = (u32)f2bf(ov[2]) | ((u32)f2bf(ov[3]) << 16);
  *(u32x2*)&outb[base] = r;
}

// ---------- launcher ----------
extern "C" void kernel_launch(void* const* d_in, const int* in_sizes, int n_in,
                              void* d_out, int out_size, void* d_ws, size_t ws_size,
                              hipStream_t stream) {
  const float* x = (const float*)d_in[0];
  const float* c_attn_w = (const float*)d_in[1];
  const float* conv_w = (const float*)d_in[2];
  const float* ln_comp_w = (const float*)d_in[3];
  const float* ln_local_w = (const float*)d_in[4];
  const float* gate_w1 = (const float*)d_in[5];
  const float* gate_ln_w = (const float*)d_in[6];
  const float* gate_w2 = (const float*)d_in[7];
  const float* c_proj_w = (const float*)d_in[8];
  float* y = (float*)d_out;

  char* ws = (char*)d_ws;
  size_t off = 0;
  auto alloc = [&](size_t bytes) -> void* {
    void* p = ws + off;
    off += (bytes + 255) & ~(size_t)255;
    return p;
  };
  u16* qkvb = (u16*)alloc((size_t)8192 * 3072 * 2);
  u16* xb = (u16*)alloc((size_t)8192 * 1024 * 2);
  u16* wab = (u16*)alloc((size_t)3072 * 1024 * 2);
  u16* wpb = (u16*)alloc((size_t)1024 * 1024 * 2);
  u16* wcb = (u16*)alloc((size_t)64 * 2048 * 2);
  u16* kcb = (u16*)alloc((size_t)128 * 4096 * 2);  // [bh][nb(64)][d] bf16
  u16* vcb = (u16*)alloc((size_t)128 * 4096 * 2);  // [bh][d][nb(64)] bf16
  u16* locb = (u16*)alloc((size_t)8192 * 1024 * 2);
  u16* compb = (u16*)alloc((size_t)8192 * 1024 * 2);
  float* feats = (float*)alloc((size_t)8 * 2048 * 4);
  float* hraw = (float*)alloc((size_t)8192 * 4);
  float* gates = (float*)alloc(64);
  u16* combb = (u16*)alloc((size_t)8192 * 1024 * 2);

  fused_cast<<<12801, 256, 0, stream>>>(x, c_attn_w, c_proj_w, conv_w, xb, wab, wpb, wcb, kcb,
                                        vcb);

  gemm_bt<1><<<dim3(64, 24), 256, 0, stream>>>(xb, wab, qkvb, 8192, 3072, 1024);

  compress_kernel<<<dim3(126, 2), 256, 0, stream>>>(qkvb, wcb, ln_comp_w, kcb, vcb);

  attn_fused<<<dim3(128, 16), 256, 0, stream>>>(qkvb, kcb, vcb, locb, compb);

  ln_feats<<<8, 256, 0, stream>>>(locb, compb, ln_local_w, feats);
  gate_gemv<<<256, 256, 0, stream>>>(feats, gate_w1, hraw);
  gate_fin<<<8, 256, 0, stream>>>(hraw, gate_ln_w, gate_w2, gates);

  combine_ln_cast<<<8192, 256, 0, stream>>>(locb, compb, ln_local_w, gates, combb);

  gemm_bt<0><<<dim3(64, 8), 256, 0, stream>>>(combb, wpb, y, 8192, 1024, 1024);
}

// Round 6
// 280.160 us; speedup vs baseline: 3.4154x; 1.0712x over previous
//
#include <hip/hip_runtime.h>
#include <cstdint>
#include <cmath>
#include <cstddef>

typedef unsigned int u32;
typedef unsigned short u16;
typedef __bf16 bf16x8 __attribute__((ext_vector_type(8)));
typedef float f32x4 __attribute__((ext_vector_type(4)));
typedef u32 u32x4 __attribute__((ext_vector_type(4)));
typedef u32 u32x2 __attribute__((ext_vector_type(2)));

#define DEV static __device__ __forceinline__

// ---------- helpers ----------
DEV float bflo(u32 u) { return __uint_as_float(u << 16); }
DEV float bfhi(u32 u) { return __uint_as_float(u & 0xffff0000u); }
DEV u16 f2bf(float f) {               // RNE fp32 -> bf16
  u32 u = __float_as_uint(f);
  u += 0x7fffu + ((u >> 16) & 1u);
  return (u16)(u >> 16);
}
DEV f32x4 unpack_bf4(u32x2 r) {
  return (f32x4){bflo(r[0]), bfhi(r[0]), bflo(r[1]), bfhi(r[1])};
}
DEV float wredsum(float v) {
#pragma unroll
  for (int o = 32; o; o >>= 1) v += __shfl_xor(v, o, 64);
  return v;
}

// async global->LDS, 16B per lane. LDS dest is wave-uniform base + lane*16.
DEV void gload_lds16(const u16* g, u16* lds_base) {
  __builtin_amdgcn_global_load_lds((const __attribute__((address_space(1))) void*)g,
                                   (__attribute__((address_space(3))) void*)lds_base,
                                   16, 0, 0);
}

// ---------- fused casts + workspace pad zeroing ----------
__global__ __launch_bounds__(256) void fused_cast(const float* __restrict__ x,
                                                  const float* __restrict__ aw,
                                                  const float* __restrict__ pw,
                                                  const float* __restrict__ cw,
                                                  u16* __restrict__ xb,
                                                  u16* __restrict__ wab,
                                                  u16* __restrict__ wpb,
                                                  u16* __restrict__ wcb,
                                                  u16* __restrict__ kcb,
                                                  u16* __restrict__ vcb) {
  const int blk = blockIdx.x;
  if (blk < 12288) {
    const float* src;
    u16* dst;
    int base;
    if (blk < 8192) { src = x; dst = xb; base = blk; }
    else if (blk < 11264) { src = aw; dst = wab; base = blk - 8192; }
    else { src = pw; dst = wpb; base = blk - 11264; }
    const size_t idx = ((size_t)base * 256 + threadIdx.x) * 4;
    const f32x4 v = *(const f32x4*)&src[idx];
    u32x2 r;
    r[0] = (u32)f2bf(v[0]) | ((u32)f2bf(v[1]) << 16);
    r[1] = (u32)f2bf(v[2]) | ((u32)f2bf(v[3]) << 16);
    *(u32x2*)&dst[idx] = r;
  } else if (blk < 12800) {
    // conv_w [64][64][32] (o,i,kk) fp32 -> Wc[o][kk*64+i] bf16
    const int idx = (blk - 12288) * 256 + threadIdx.x;
    const int o = idx >> 11;
    const int rest = idx & 2047;
    const int i = rest >> 5;
    const int kk = rest & 31;
    wcb[(o << 11) + (kk << 6) + i] = f2bf(cw[idx]);
  } else {
    for (int i = threadIdx.x; i < 8192; i += 256) {
      const int bh = i >> 6, d = i & 63;
      kcb[bh * 4096 + 63 * 64 + d] = 0;   // K-block row 63 (pad)
      vcb[bh * 4096 + d * 64 + 63] = 0;   // V col 63 (pad)
    }
  }
}

// ---------- MFMA GEMM: out[M,N] = A[M,K](bf16) * B[N,K](bf16)^T ----------
// 128x128 tile, BK=64, 256 threads; global_load_lds width=16.
// XOR-swizzled LDS: logical k-group L (8 groups of 8 halfwords) at row r lives
// at physical group L^(r&7). Staging stays lane-contiguous (wave-uniform base,
// per-lane source remap); reads spread 16 lr-lanes over all 32 banks.
template <int OUT_BF16>
__global__ __launch_bounds__(256, 4) void gemm_bt(const u16* __restrict__ A,
                                                  const u16* __restrict__ Bm,
                                                  void* __restrict__ out,
                                                  int M, int N, int K) {
  __shared__ u16 As[128 * 64];
  __shared__ u16 Bs[128 * 64];
  const int tid = threadIdx.x;
  const int lane = tid & 63;
  const int w = tid >> 6;
  const int row0 = blockIdx.x * 128;
  const int col0 = blockIdx.y * 128;
  const int wm = (w >> 1) * 64, wn = (w & 1) * 64;
  const int lr = lane & 15, lq = lane >> 4;
  // staging: lane covers row (chunk base + lane>>3), physical group lane&7;
  // source logical group = (lane&7) ^ ((lane>>3)&7)
  const int srow = lane >> 3;
  const int scol = ((lane & 7) ^ (srow & 7)) * 8;
  // read swizzle: halfword offset of logical group ks*4+lq at row (..+lr)
  const int pgA = ((lq ^ (lr & 7)) * 8);  // ks=0; ks=1 is pgA ^ 32

  f32x4 acc[4][4] = {};

  for (int k0 = 0; k0 < K; k0 += 64) {
    __syncthreads();
#pragma unroll
    for (int c = 0; c < 4; ++c) {
      const int base_r = w * 32 + c * 8;   // wave-uniform
      gload_lds16(&A[(size_t)(row0 + base_r + srow) * K + k0 + scol], &As[base_r * 64]);
      gload_lds16(&Bm[(size_t)(col0 + base_r + srow) * K + k0 + scol], &Bs[base_r * 64]);
    }
    __syncthreads();
#pragma unroll
    for (int ks = 0; ks < 2; ++ks) {
      const int pg = pgA ^ (ks << 5);
      bf16x8 af[4], bfr[4];
#pragma unroll
      for (int i = 0; i < 4; ++i) {
        af[i] = *(const bf16x8*)&As[(wm + i * 16 + lr) * 64 + pg];
        bfr[i] = *(const bf16x8*)&Bs[(wn + i * 16 + lr) * 64 + pg];
      }
#pragma unroll
      for (int i = 0; i < 4; ++i)
#pragma unroll
        for (int j = 0; j < 4; ++j)
          acc[i][j] = __builtin_amdgcn_mfma_f32_16x16x32_bf16(af[i], bfr[j], acc[i][j], 0, 0, 0);
    }
  }
#pragma unroll
  for (int i = 0; i < 4; ++i)
#pragma unroll
    for (int j = 0; j < 4; ++j)
#pragma unroll
      for (int rr = 0; rr < 4; ++rr) {
        const int gr = row0 + wm + i * 16 + lq * 4 + rr;
        const int gc = col0 + wn + j * 16 + lr;
        const float v = acc[i][j][rr];
        if (OUT_BF16)
          ((u16*)out)[(size_t)gr * N + gc] = f2bf(v);
        else
          ((float*)out)[(size_t)gr * N + gc] = v;
      }
}

// ---------- compression: conv(K=32,stride16) as GEMM + LN(64) + GELU ----------
// BM=32 tiles, grid (252, 2) ~= 2 blocks/CU for TLP latency cover.
// y=0 -> kcb[bh][nb][d], y=1 -> vcb[bh][d][nb] (both bf16).
__global__ __launch_bounds__(256) void compress_kernel(const u16* __restrict__ qkv,
                                                       const u16* __restrict__ Wc,
                                                       const float* __restrict__ ln_w,
                                                       u16* __restrict__ kcb,
                                                       u16* __restrict__ vcb) {
  __shared__ u16 As[2][32 * 32];
  __shared__ u16 Bs[2][64 * 32];
  __shared__ float Cs[32][65];
  const int tid = threadIdx.x;
  const int lane = tid & 63, w = tid >> 6;
  const int lr = lane & 15, lq = lane >> 4;
  const int r0 = blockIdx.x * 32;
  const int srcoff = 1024 + (int)blockIdx.y * 1024;

  // staging sources: B rows w*16+(lane>>2); A (waves 0,1 only) rows w*16+(lane>>2)
  const int srow = lane >> 2, scol = (lane & 3) * 8;
  const size_t bbase = (size_t)(w * 16 + srow) * 2048 + scol;
  size_t abase = 0;
  if (w < 2) {
    const int gr = r0 + w * 16 + srow;
    const int bh = gr / 63;
    const int nb = gr - bh * 63;
    const int b = bh >> 4, h = bh & 15;
    abase = (size_t)(b * 1024 + nb * 16) * 3072 + srcoff + h * 64 + scol;
  }
  const int rw = (w & 1) * 16;   // row-half this wave computes
  const int cw = (w >> 1) * 32;  // col-half this wave computes

  f32x4 acc[2] = {};
  // prologue stage k0=0 into buf 0
  gload_lds16(&Wc[bbase], &Bs[0][w * 512]);
  if (w < 2) gload_lds16(&qkv[abase], &As[0][w * 512]);
  for (int it = 0; it < 64; ++it) {
    const int cur = it & 1;
    __syncthreads();  // drains stage for buf cur
    if (it < 63) {
      const int k0 = (it + 1) * 32;
      const int kk = k0 >> 6, i0 = k0 & 63;
      gload_lds16(&Wc[bbase + k0], &Bs[cur ^ 1][w * 512]);
      if (w < 2) gload_lds16(&qkv[abase + (size_t)kk * 3072 + i0], &As[cur ^ 1][w * 512]);
    }
    const bf16x8 af = *(const bf16x8*)&As[cur][(rw + lr) * 32 + lq * 8];
#pragma unroll
    for (int j = 0; j < 2; ++j) {
      const bf16x8 bfr = *(const bf16x8*)&Bs[cur][(cw + j * 16 + lr) * 32 + lq * 8];
      acc[j] = __builtin_amdgcn_mfma_f32_16x16x32_bf16(af, bfr, acc[j], 0, 0, 0);
    }
  }
  __syncthreads();
#pragma unroll
  for (int j = 0; j < 2; ++j)
#pragma unroll
    for (int rr = 0; rr < 4; ++rr)
      Cs[rw + lq * 4 + rr][cw + j * 16 + lr] = acc[j][rr];
  __syncthreads();
  if (tid < 32) {
    const int gr2 = r0 + tid;
    const int bh2 = gr2 / 63;
    const int nb2 = gr2 - bh2 * 63;
    float s = 0.f, s2 = 0.f;
#pragma unroll 8
    for (int d = 0; d < 64; ++d) {
      const float xv = Cs[tid][d];
      s += xv;
      s2 += xv * xv;
    }
    const float m = s * (1.f / 64.f);
    const float inv = rsqrtf(s2 * (1.f / 64.f) - m * m + 1e-5f);
    if (blockIdx.y == 0) {
      const size_t gb = (size_t)bh2 * 4096 + nb2 * 64;
#pragma unroll 8
      for (int d = 0; d < 64; ++d) {
        const float z = (Cs[tid][d] - m) * inv * ln_w[d];
        kcb[gb + d] = f2bf(0.5f * z * (1.f + erff(z * 0.70710678118f)));
      }
    } else {
      const size_t gb = (size_t)bh2 * 4096 + nb2;
#pragma unroll 8
      for (int d = 0; d < 64; ++d) {
        const float z = (Cs[tid][d] - m) * inv * ln_w[d];
        vcb[gb + d * 64] = f2bf(0.5f * z * (1.f + erff(z * 0.70710678118f)));
      }
    }
  }
}

// ---------- fused attention: local banded (window 129) + compressed-KV ----------
// grid (B*H, T/64); block 256 = 4 waves; wave w owns query rows w*16..w*16+15.
// Local phase computes only band tiles j in [w, w+8] (9 of 12).
__global__ __launch_bounds__(256) void attn_fused(const u16* __restrict__ qkv,
                                                  const u16* __restrict__ kcb,
                                                  const u16* __restrict__ vcb,
                                                  u16* __restrict__ loc,
                                                  u16* __restrict__ outc) {
  __shared__ __align__(16) char smem[53248];
  u16* Ks = (u16*)smem;            // [192][72] bf16, local phase 1
  u16* Vt = (u16*)smem;            // [64][200] bf16, local phase 2 (overlays Ks)
  u16* Ps = (u16*)(smem + 27648);  // [64][200] bf16
  const int bh = blockIdx.x;
  const int b = bh >> 4, h = bh & 15;
  const int i0 = blockIdx.y * 64;
  const int jbase = i0 - 128;
  const int tid = threadIdx.x;
  const int lane = tid & 63, w = tid >> 6;
  const int lr = lane & 15, lq = lane >> 4;

  // stage K into LDS, V into regs; Q fragments from global
  u32x4 vreg[6];
#pragma unroll
  for (int c = 0; c < 6; ++c) {
    const int lin = c * 256 + tid;
    const int s = lin >> 3, d0 = (lin & 7) * 8;
    const int j = jbase + s;
    u32x4 kval = {0, 0, 0, 0}, vval = {0, 0, 0, 0};
    if (j >= 0) {
      const size_t ro = (size_t)(b * 1024 + j) * 3072 + h * 64 + d0;
      kval = *(const u32x4*)&qkv[ro + 1024];
      vval = *(const u32x4*)&qkv[ro + 2048];
    }
    vreg[c] = vval;
    *(u32x4*)&Ks[s * 72 + d0] = kval;
  }
  bf16x8 qf[2];
  {
    const size_t qrow = (size_t)(b * 1024 + i0 + w * 16 + lr) * 3072 + h * 64;
#pragma unroll
    for (int ks = 0; ks < 2; ++ks) qf[ks] = *(const bf16x8*)&qkv[qrow + ks * 32 + lq * 8];
  }
  __syncthreads();

  // S = Q*K^T over the 9 band tiles jt = w..w+8
  f32x4 sa[9];
#pragma unroll
  for (int j9 = 0; j9 < 9; ++j9) sa[j9] = (f32x4){0.f, 0.f, 0.f, 0.f};
#pragma unroll
  for (int ks = 0; ks < 2; ++ks)
#pragma unroll
    for (int j9 = 0; j9 < 9; ++j9) {
      const int jt = w + j9;
      const bf16x8 kf = *(const bf16x8*)&Ks[(jt * 16 + lr) * 72 + ks * 32 + lq * 8];
      sa[j9] = __builtin_amdgcn_mfma_f32_16x16x32_bf16(qf[ks], kf, sa[j9], 0, 0, 0);
    }

  const float NINF = -__builtin_inff();
  float mx[4] = {NINF, NINF, NINF, NINF};
#pragma unroll
  for (int j9 = 0; j9 < 9; ++j9) {
    const int s = (w + j9) * 16 + lr;
#pragma unroll
    for (int rr = 0; rr < 4; ++rr) {
      const int qi = w * 16 + lq * 4 + rr;
      const bool valid = (jbase + s >= 0) && (s >= qi) && (s <= qi + 128);
      const float v = valid ? sa[j9][rr] * 0.125f : NINF;
      sa[j9][rr] = v;
      mx[rr] = fmaxf(mx[rr], v);
    }
  }
#pragma unroll
  for (int rr = 0; rr < 4; ++rr)
#pragma unroll
    for (int o = 1; o < 16; o <<= 1) mx[rr] = fmaxf(mx[rr], __shfl_xor(mx[rr], o, 64));
  float sum[4] = {0.f, 0.f, 0.f, 0.f};
#pragma unroll
  for (int j9 = 0; j9 < 9; ++j9)
#pragma unroll
    for (int rr = 0; rr < 4; ++rr) {
      const float p = __expf(sa[j9][rr] - mx[rr]);
      sa[j9][rr] = p;
      sum[rr] += p;
    }
#pragma unroll
  for (int rr = 0; rr < 4; ++rr) {
#pragma unroll
    for (int o = 1; o < 16; o <<= 1) sum[rr] += __shfl_xor(sum[rr], o, 64);
    sum[rr] = 1.0f / sum[rr];
  }
  __syncthreads();  // Ks reads done before Vt overlays

  // write P (9 tiles + 1 zero tile to cover the 160-wide PV window) and Vt
#pragma unroll
  for (int j9 = 0; j9 < 9; ++j9) {
    const int jt = w + j9;
#pragma unroll
    for (int rr = 0; rr < 4; ++rr)
      Ps[(w * 16 + lq * 4 + rr) * 200 + jt * 16 + lr] = f2bf(sa[j9][rr] * sum[rr]);
  }
  {
    const int jz = (w == 0) ? 9 : (w == 1) ? 0 : (w == 2) ? 11 : 2;
#pragma unroll
    for (int rr = 0; rr < 4; ++rr) Ps[(w * 16 + lq * 4 + rr) * 200 + jz * 16 + lr] = 0;
  }
#pragma unroll
  for (int c = 0; c < 6; ++c) {
    const int lin = c * 256 + tid;
    const int s = lin >> 3, d0 = (lin & 7) * 8;
    const u32x4 val = vreg[c];
#pragma unroll
    for (int q = 0; q < 4; ++q) {
      Vt[(d0 + 2 * q) * 200 + s] = (u16)(val[q] & 0xffffu);
      Vt[(d0 + 2 * q + 1) * 200 + s] = (u16)(val[q] >> 16);
    }
  }
  __syncthreads();

  // O = P*V over the wave's 160-wide window (5 K-steps)
  const int W = (w >> 1) * 32;  // halfword offset of the window
  f32x4 oa[4];
#pragma unroll
  for (int jt = 0; jt < 4; ++jt) oa[jt] = (f32x4){0.f, 0.f, 0.f, 0.f};
#pragma unroll
  for (int ks = 0; ks < 5; ++ks) {
    const bf16x8 pf = *(const bf16x8*)&Ps[(w * 16 + lr) * 200 + W + ks * 32 + lq * 8];
#pragma unroll
    for (int jt = 0; jt < 4; ++jt) {
      const bf16x8 vf = *(const bf16x8*)&Vt[(jt * 16 + lr) * 200 + W + ks * 32 + lq * 8];
      oa[jt] = __builtin_amdgcn_mfma_f32_16x16x32_bf16(pf, vf, oa[jt], 0, 0, 0);
    }
  }
#pragma unroll
  for (int jt = 0; jt < 4; ++jt)
#pragma unroll
    for (int rr = 0; rr < 4; ++rr)
      loc[(size_t)(b * 1024 + i0 + w * 16 + lq * 4 + rr) * 1024 + h * 64 + jt * 16 + lr] =
          f2bf(oa[jt][rr]);

  // ===== compressed-KV phase (reuses qf and smem) =====
  __syncthreads();
  u16* Kc = (u16*)smem;                  // [64][72]
  u16* Vc = (u16*)(smem + 9216);         // [64][72]
  u16* Pc = (u16*)(smem + 18432);        // [64][72]
  const size_t cb = (size_t)bh * 4096;
  for (int c2 = tid; c2 < 512; c2 += 256) {
    const int nb = c2 >> 3, d0 = (c2 & 7) * 8;
    *(u32x4*)&Kc[nb * 72 + d0] = *(const u32x4*)&kcb[cb + nb * 64 + d0];
  }
  for (int c2 = tid; c2 < 512; c2 += 256) {
    const int d = c2 >> 3, n0 = (c2 & 7) * 8;
    *(u32x4*)&Vc[d * 72 + n0] = *(const u32x4*)&vcb[cb + d * 64 + n0];
  }
  __syncthreads();

  f32x4 ca[4];
#pragma unroll
  for (int j = 0; j < 4; ++j) ca[j] = (f32x4){0.f, 0.f, 0.f, 0.f};
#pragma unroll
  for (int ks = 0; ks < 2; ++ks)
#pragma unroll
    for (int j = 0; j < 4; ++j) {
      const bf16x8 kf = *(const bf16x8*)&Kc[(j * 16 + lr) * 72 + ks * 32 + lq * 8];
      ca[j] = __builtin_amdgcn_mfma_f32_16x16x32_bf16(qf[ks], kf, ca[j], 0, 0, 0);
    }
  float mc[4] = {NINF, NINF, NINF, NINF};
#pragma unroll
  for (int j = 0; j < 4; ++j) {
    const int s = j * 16 + lr;
#pragma unroll
    for (int rr = 0; rr < 4; ++rr) {
      const int i = i0 + w * 16 + lq * 4 + rr;
      const bool valid = (s <= i) && (s < 63);
      const float v = valid ? ca[j][rr] * 0.125f : NINF;
      ca[j][rr] = v;
      mc[rr] = fmaxf(mc[rr], v);
    }
  }
#pragma unroll
  for (int rr = 0; rr < 4; ++rr)
#pragma unroll
    for (int o = 1; o < 16; o <<= 1) mc[rr] = fmaxf(mc[rr], __shfl_xor(mc[rr], o, 64));
  float sc[4] = {0.f, 0.f, 0.f, 0.f};
#pragma unroll
  for (int j = 0; j < 4; ++j)
#pragma unroll
    for (int rr = 0; rr < 4; ++rr) {
      const float p = __expf(ca[j][rr] - mc[rr]);
      ca[j][rr] = p;
      sc[rr] += p;
    }
#pragma unroll
  for (int rr = 0; rr < 4; ++rr) {
#pragma unroll
    for (int o = 1; o < 16; o <<= 1) sc[rr] += __shfl_xor(sc[rr], o, 64);
    sc[rr] = 1.0f / sc[rr];
  }
#pragma unroll
  for (int j = 0; j < 4; ++j)
#pragma unroll
    for (int rr = 0; rr < 4; ++rr)
      Pc[(w * 16 + lq * 4 + rr) * 72 + j * 16 + lr] = f2bf(ca[j][rr] * sc[rr]);
  __syncthreads();

  f32x4 co[4];
#pragma unroll
  for (int jt = 0; jt < 4; ++jt) co[jt] = (f32x4){0.f, 0.f, 0.f, 0.f};
#pragma unroll
  for (int ks = 0; ks < 2; ++ks) {
    const bf16x8 pf = *(const bf16x8*)&Pc[(w * 16 + lr) * 72 + ks * 32 + lq * 8];
#pragma unroll
    for (int jt = 0; jt < 4; ++jt) {
      const bf16x8 vf = *(const bf16x8*)&Vc[(jt * 16 + lr) * 72 + ks * 32 + lq * 8];
      co[jt] = __builtin_amdgcn_mfma_f32_16x16x32_bf16(pf, vf, co[jt], 0, 0, 0);
    }
  }
#pragma unroll
  for (int jt = 0; jt < 4; ++jt)
#pragma unroll
    for (int rr = 0; rr < 4; ++rr)
      outc[(size_t)(b * 1024 + i0 + w * 16 + lq * 4 + rr) * 1024 + h * 64 + jt * 16 + lr] =
          f2bf(co[jt][rr]);
}

// ---------- LN of the 8 last-token local rows + pack feats[8][2048] ----------
__global__ __launch_bounds__(256) void ln_feats(const u16* __restrict__ locb,
                                                const u16* __restrict__ compb,
                                                const float* __restrict__ lnw,
                                                float* __restrict__ feats) {
  const int b = blockIdx.x, tid = threadIdx.x;
  const size_t base = ((size_t)b * 1024 + 1023) * 1024 + tid * 4;
  const f32x4 v = unpack_bf4(*(const u32x2*)&locb[base]);
  float s = v[0] + v[1] + v[2] + v[3];
  float s2 = v[0] * v[0] + v[1] * v[1] + v[2] * v[2] + v[3] * v[3];
  s = wredsum(s);
  s2 = wredsum(s2);
  __shared__ float rs[4], rs2[4];
  const int w = tid >> 6, lane = tid & 63;
  if (!lane) { rs[w] = s; rs2[w] = s2; }
  __syncthreads();
  s = rs[0] + rs[1] + rs[2] + rs[3];
  s2 = rs2[0] + rs2[1] + rs2[2] + rs2[3];
  const float m = s * (1.f / 1024.f);
  const float inv = rsqrtf(s2 * (1.f / 1024.f) - m * m + 1e-5f);
  const f32x4 wv = *(const f32x4*)&lnw[tid * 4];
  f32x4 o;
#pragma unroll
  for (int k = 0; k < 4; ++k) o[k] = (v[k] - m) * inv * wv[k];
  *(f32x4*)&feats[b * 2048 + tid * 4] = o;
  *(f32x4*)&feats[b * 2048 + 1024 + tid * 4] = unpack_bf4(*(const u32x2*)&compb[base]);
}

// ---------- gating GEMV: hraw[b,o] = feats[b,:] . w1[o,:] ----------
__global__ __launch_bounds__(256) void gate_gemv(const float* __restrict__ feats,
                                                 const float* __restrict__ w1,
                                                 float* __restrict__ hraw) {
  const int o = blockIdx.x * 4 + (threadIdx.x >> 6);
  const int lane = threadIdx.x & 63;
  const float* wr = &w1[(size_t)o * 2048];
  float acc[8] = {};
#pragma unroll
  for (int it = 0; it < 8; ++it) {
    const int c = (it * 64 + lane) * 4;
    const f32x4 wv = *(const f32x4*)&wr[c];
#pragma unroll
    for (int b = 0; b < 8; ++b) {
      const f32x4 fv = *(const f32x4*)&feats[b * 2048 + c];
      acc[b] += fv[0] * wv[0] + fv[1] * wv[1] + fv[2] * wv[2] + fv[3] * wv[3];
    }
  }
#pragma unroll
  for (int b = 0; b < 8; ++b) acc[b] = wredsum(acc[b]);
  if (lane == 0) {
#pragma unroll
    for (int b = 0; b < 8; ++b) hraw[b * 1024 + o] = acc[b];
  }
}

// ---------- gating finalize: LN + ReLU + 2-way GEMV + softmax ----------
__global__ __launch_bounds__(256) void gate_fin(const float* __restrict__ hraw,
                                                const float* __restrict__ lnw,
                                                const float* __restrict__ w2,
                                                float* __restrict__ gates) {
  const int b = blockIdx.x, tid = threadIdx.x;
  const f32x4 v = *(const f32x4*)&hraw[(size_t)b * 1024 + tid * 4];
  float s = v[0] + v[1] + v[2] + v[3];
  float s2 = v[0] * v[0] + v[1] * v[1] + v[2] * v[2] + v[3] * v[3];
  s = wredsum(s);
  s2 = wredsum(s2);
  __shared__ float rs[4], rs2[4];
  const int w = tid >> 6, lane = tid & 63;
  if (!lane) { rs[w] = s; rs2[w] = s2; }
  __syncthreads();
  s = rs[0] + rs[1] + rs[2] + rs[3];
  s2 = rs2[0] + rs2[1] + rs2[2] + rs2[3];
  const float m = s * (1.f / 1024.f);
  const float inv = rsqrtf(s2 * (1.f / 1024.f) - m * m + 1e-5f);
  float p0 = 0.f, p1 = 0.f;
#pragma unroll
  for (int k = 0; k < 4; ++k) {
    float hh = (v[k] - m) * inv * lnw[tid * 4 + k];
    hh = fmaxf(hh, 0.f);
    p0 += hh * w2[tid * 4 + k];
    p1 += hh * w2[1024 + tid * 4 + k];
  }
  p0 = wredsum(p0);
  p1 = wredsum(p1);
  __syncthreads();
  if (!lane) { rs[w] = p0; rs2[w] = p1; }
  __syncthreads();
  if (tid == 0) {
    const float l0 = rs[0] + rs[1] + rs[2] + rs[3];
    const float l1 = rs2[0] + rs2[1] + rs2[2] + rs2[3];
    const float mm = fmaxf(l0, l1);
    const float e0 = __expf(l0 - mm), e1 = __expf(l1 - mm);
    const float iv = 1.f / (e0 + e1);
    gates[b * 2] = e0 * iv;
    gates[b * 2 + 1] = e1 * iv;
  }
}

// ---------- fused: per-row LN of local_out + gate-combine + bf16 cast ----------
__global__ __launch_bounds__(256) void combine_ln_cast(const u16* __restrict__ locb,
                                                       const u16* __restrict__ compb,
                                                       const float* __restrict__ lnw,
                                                       const float* __restrict__ gates,
                                                       u16* __restrict__ outb) {
  const int row = blockIdx.x, tid = threadIdx.x;
  const size_t base = (size_t)row * 1024 + tid * 4;
  const f32x4 v = unpack_bf4(*(const u32x2*)&locb[base]);
  float s = v[0] + v[1] + v[2] + v[3];
  float s2 = v[0] * v[0] + v[1] * v[1] + v[2] * v[2] + v[3] * v[3];
  s = wredsum(s);
  s2 = wredsum(s2);
  __shared__ float rs[4], rs2[4];
  const int w = tid >> 6, lane = tid & 63;
  if (!lane) { rs[w] = s; rs2[w] = s2; }
  __syncthreads();
  s = rs[0] + rs[1] + rs[2] + rs[3];
  s2 = rs2[0] + rs2[1] + rs2[2] + rs2[3];
  const float m = s * (1.f / 1024.f);
  const float inv = rsqrtf(s2 * (1.f / 1024.f) - m * m + 1e-5f);
  const int b = row >> 10;
  const float g0 = gates[2 * b], g1 = gates[2 * b + 1];
  const f32x4 wv = *(const f32x4*)&lnw[tid * 4];
  const f32x4 c = unpack_bf4(*(const u32x2*)&compb[base]);
  float ov[4];
#pragma unroll
  for (int k = 0; k < 4; ++k) ov[k] = g0 * ((v[k] - m) * inv * wv[k]) + g1 * c[k];
  u32x2 r;
  r[0] = (u32)f2bf(ov[0]) | ((u32)f2bf(ov[1]) << 16);
  r[1] = (u32)f2bf(ov[2]) | ((u32)f2bf(ov[3]) << 16);
  *(u32x2*)&outb[base] = r;
}

// ---------- launcher ----------
extern "C" void kernel_launch(void* const* d_in, const int* in_sizes, int n_in,
                              void* d_out, int out_size, void* d_ws, size_t ws_size,
                              hipStream_t stream) {
  const float* x = (const float*)d_in[0];
  const float* c_attn_w = (const float*)d_in[1];
  const float* conv_w = (const float*)d_in[2];
  const float* ln_comp_w = (const float*)d_in[3];
  const float* ln_local_w = (const float*)d_in[4];
  const float* gate_w1 = (const float*)d_in[5];
  const float* gate_ln_w = (const float*)d_in[6];
  const float* gate_w2 = (const float*)d_in[7];
  const float* c_proj_w = (const float*)d_in[8];
  float* y = (float*)d_out;

  char* ws = (char*)d_ws;
  size_t off = 0;
  auto alloc = [&](size_t bytes) -> void* {
    void* p = ws + off;
    off += (bytes + 255) & ~(size_t)255;
    return p;
  };
  u16* qkvb = (u16*)alloc((size_t)8192 * 3072 * 2);
  u16* xb = (u16*)alloc((size_t)8192 * 1024 * 2);
  u16* wab = (u16*)alloc((size_t)3072 * 1024 * 2);
  u16* wpb = (u16*)alloc((size_t)1024 * 1024 * 2);
  u16* wcb = (u16*)alloc((size_t)64 * 2048 * 2);
  u16* kcb = (u16*)alloc((size_t)128 * 4096 * 2);  // [bh][nb(64)][d] bf16
  u16* vcb = (u16*)alloc((size_t)128 * 4096 * 2);  // [bh][d][nb(64)] bf16
  u16* locb = (u16*)alloc((size_t)8192 * 1024 * 2);
  u16* compb = (u16*)alloc((size_t)8192 * 1024 * 2);
  float* feats = (float*)alloc((size_t)8 * 2048 * 4);
  float* hraw = (float*)alloc((size_t)8192 * 4);
  float* gates = (float*)alloc(64);
  u16* combb = (u16*)alloc((size_t)8192 * 1024 * 2);

  fused_cast<<<12801, 256, 0, stream>>>(x, c_attn_w, c_proj_w, conv_w, xb, wab, wpb, wcb, kcb,
                                        vcb);

  gemm_bt<1><<<dim3(64, 24), 256, 0, stream>>>(xb, wab, qkvb, 8192, 3072, 1024);

  compress_kernel<<<dim3(252, 2), 256, 0, stream>>>(qkvb, wcb, ln_comp_w, kcb, vcb);

  attn_fused<<<dim3(128, 16), 256, 0, stream>>>(qkvb, kcb, vcb, locb, compb);

  ln_feats<<<8, 256, 0, stream>>>(locb, compb, ln_local_w, feats);
  gate_gemv<<<256, 256, 0, stream>>>(feats, gate_w1, hraw);
  gate_fin<<<8, 256, 0, stream>>>(hraw, gate_ln_w, gate_w2, gates);

  combine_ln_cast<<<8192, 256, 0, stream>>>(locb, compb, ln_local_w, gates, combb);

  gemm_bt<0><<<dim3(64, 8), 256, 0, stream>>>(combb, wpb, y, 8192, 1024, 1024);
}